// Round 1
// baseline (2272.390 us; speedup 1.0000x reference)
//
#include <hip/hip_runtime.h>
#include <math.h>

// Problem constants (from reference): N=50000, D_IN=512, D_HID=512, D_OUT=256
#define DIN  512
#define DHID 512
#define DOUT 256

// ---------------------------------------------------------------------------
// CSR build: count in-degrees
__global__ void k_count(const int* __restrict__ dst, int* __restrict__ deg, int E) {
    int e = blockIdx.x * blockDim.x + threadIdx.x;
    if (e < E) atomicAdd(&deg[dst[e]], 1);
}

// Single-block exclusive scan: deg[0..n) -> rowptr[0..n], rowptr[n]=total
__global__ void k_scan(const int* __restrict__ deg, int* __restrict__ rowptr, int n) {
    __shared__ int sdata[1024];
    __shared__ int s_carry;
    int tid = threadIdx.x;
    if (tid == 0) s_carry = 0;
    __syncthreads();
    for (int base = 0; base < n; base += 1024) {
        int i = base + tid;
        int v = (i < n) ? deg[i] : 0;
        sdata[tid] = v;
        __syncthreads();
        for (int off = 1; off < 1024; off <<= 1) {
            int t = (tid >= off) ? sdata[tid - off] : 0;
            __syncthreads();
            sdata[tid] += t;
            __syncthreads();
        }
        int incl = sdata[tid];
        if (i < n) rowptr[i] = s_carry + (incl - v);
        __syncthreads();
        if (tid == 1023) s_carry += sdata[1023];
        __syncthreads();
    }
    if (tid == 0) rowptr[n] = s_carry;
}

// Fill CSR column list (cursor pre-initialized to rowptr copy)
__global__ void k_fill(const int* __restrict__ src, const int* __restrict__ dst,
                       int* __restrict__ cursor, int* __restrict__ col, int E) {
    int e = blockIdx.x * blockDim.x + threadIdx.x;
    if (e < E) {
        int p = atomicAdd(&cursor[dst[e]], 1);
        col[p] = src[e];
    }
}

// ---------------------------------------------------------------------------
// Mean aggregation, D=512. One wave (64 lanes) per dst node; each lane holds
// 8 floats (2 x float4). Gather rows are 2 KB coalesced float4 reads.
__global__ void k_aggregate(const float* __restrict__ X, const int* __restrict__ rowptr,
                            const int* __restrict__ col, float* __restrict__ A, int n) {
    int node = blockIdx.x * (blockDim.x >> 6) + (threadIdx.x >> 6);
    int lane = threadIdx.x & 63;
    if (node >= n) return;
    int beg = rowptr[node], end = rowptr[node + 1];
    float4 a0 = make_float4(0.f, 0.f, 0.f, 0.f);
    float4 a1 = make_float4(0.f, 0.f, 0.f, 0.f);
    const float4* Xv = (const float4*)X;
    for (int e = beg; e < end; ++e) {
        const float4* row = Xv + (size_t)col[e] * 128;  // 512 floats = 128 float4
        float4 v0 = row[lane];
        float4 v1 = row[lane + 64];
        a0.x += v0.x; a0.y += v0.y; a0.z += v0.z; a0.w += v0.w;
        a1.x += v1.x; a1.y += v1.y; a1.z += v1.z; a1.w += v1.w;
    }
    float inv = 1.0f / fmaxf((float)(end - beg), 1.0f);
    a0.x *= inv; a0.y *= inv; a0.z *= inv; a0.w *= inv;
    a1.x *= inv; a1.y *= inv; a1.z *= inv; a1.w *= inv;
    float4* Av = (float4*)(A + (size_t)node * 512);
    Av[lane] = a0;
    Av[lane + 64] = a1;
}

// ---------------------------------------------------------------------------
// Dual-input SGEMM: C = act(A1 @ W1^T + A2 @ W2^T + bias)
// A1,A2: [M,K] row-major; W1,W2: [NC,K] row-major; C: [M,NC]
// BM=BN=64, BK=16, 256 threads, 4x4 microtile per thread.
#define BM 64
#define BN 64
#define BK 16

__global__ __launch_bounds__(256)
void k_gemm_dual(const float* __restrict__ A1, const float* __restrict__ W1,
                 const float* __restrict__ A2, const float* __restrict__ W2,
                 const float* __restrict__ bias, float* __restrict__ C,
                 int M, int K, int NC, int do_relu) {
    __shared__ float As[BK][BM + 1];
    __shared__ float Bs[BK][BN + 1];
    int t = threadIdx.x;
    int tx = t & 15, ty = t >> 4;
    int row0 = blockIdx.x * BM;
    int col0 = blockIdx.y * BN;
    float acc[4][4] = {};

    int r   = t >> 2;           // 0..63 (tile row for staging loads)
    int seg = (t & 3) << 2;     // 0,4,8,12 (k-segment)

    for (int p = 0; p < 2; ++p) {
        const float* Ain = p ? A2 : A1;
        const float* Win = p ? W2 : W1;
        for (int k0 = 0; k0 < K; k0 += BK) {
            int gr = row0 + r;
            float4 av = (gr < M)
                ? *(const float4*)(Ain + (size_t)gr * K + k0 + seg)
                : make_float4(0.f, 0.f, 0.f, 0.f);
            As[seg + 0][r] = av.x; As[seg + 1][r] = av.y;
            As[seg + 2][r] = av.z; As[seg + 3][r] = av.w;
            float4 bv = *(const float4*)(Win + (size_t)(col0 + r) * K + k0 + seg);
            Bs[seg + 0][r] = bv.x; Bs[seg + 1][r] = bv.y;
            Bs[seg + 2][r] = bv.z; Bs[seg + 3][r] = bv.w;
            __syncthreads();
#pragma unroll
            for (int kk = 0; kk < BK; ++kk) {
                float a[4], b[4];
#pragma unroll
                for (int i = 0; i < 4; ++i) a[i] = As[kk][ty * 4 + i];
#pragma unroll
                for (int j = 0; j < 4; ++j) b[j] = Bs[kk][tx * 4 + j];
#pragma unroll
                for (int i = 0; i < 4; ++i)
#pragma unroll
                    for (int j = 0; j < 4; ++j) acc[i][j] += a[i] * b[j];
            }
            __syncthreads();
        }
    }
#pragma unroll
    for (int i = 0; i < 4; ++i) {
        int gr = row0 + ty * 4 + i;
        if (gr >= M) continue;
#pragma unroll
        for (int j = 0; j < 4; ++j) {
            int gc = col0 + tx * 4 + j;
            float v = acc[i][j] + bias[gc];
            if (do_relu) v = fmaxf(v, 0.0f);
            C[(size_t)gr * NC + gc] = v;
        }
    }
}

// ---------------------------------------------------------------------------
// Row-wise log_softmax over DOUT=256 columns, in place. One wave per row.
__global__ void k_logsoftmax(float* __restrict__ O, int M) {
    int row = blockIdx.x * (blockDim.x >> 6) + (threadIdx.x >> 6);
    int lane = threadIdx.x & 63;
    if (row >= M) return;
    float4* rp = (float4*)(O + (size_t)row * DOUT);
    float4 v = rp[lane];
    float mx = fmaxf(fmaxf(v.x, v.y), fmaxf(v.z, v.w));
#pragma unroll
    for (int off = 32; off > 0; off >>= 1) mx = fmaxf(mx, __shfl_xor(mx, off));
    float s = expf(v.x - mx) + expf(v.y - mx) + expf(v.z - mx) + expf(v.w - mx);
#pragma unroll
    for (int off = 32; off > 0; off >>= 1) s += __shfl_xor(s, off);
    float lse = mx + logf(s);
    v.x -= lse; v.y -= lse; v.z -= lse; v.w -= lse;
    rp[lane] = v;
}

// ---------------------------------------------------------------------------
extern "C" void kernel_launch(void* const* d_in, const int* in_sizes, int n_in,
                              void* d_out, int out_size, void* d_ws, size_t ws_size,
                              hipStream_t stream) {
    const float* x   = (const float*)d_in[0];
    const int*   ei1 = (const int*)d_in[1];
    const int*   ei2 = (const int*)d_in[2];
    const float* W1l = (const float*)d_in[3];
    const float* b1  = (const float*)d_in[4];
    const float* W1r = (const float*)d_in[5];
    const float* W2l = (const float*)d_in[6];
    const float* b2  = (const float*)d_in[7];
    const float* W2r = (const float*)d_in[8];
    float* out = (float*)d_out;

    const int N  = in_sizes[0] / DIN;
    const int E1 = in_sizes[1] / 2;
    const int E2 = in_sizes[2] / 2;
    const int Emax = (E1 > E2) ? E1 : E2;

    // Workspace layout
    float* Aagg = (float*)d_ws;                       // N*512 floats
    float* H    = Aagg + (size_t)N * 512;             // N*512 floats
    int* rowptr = (int*)(H + (size_t)N * 512);        // N+1
    int* cursor = rowptr + (N + 1);                   // N
    int* deg    = cursor + N;                         // N
    int* colbuf = deg + N;                            // Emax
    (void)ws_size; (void)n_in; (void)out_size; (void)Emax;

    auto build_and_agg = [&](const int* ei, int E, const float* X) {
        const int* srcp = ei;
        const int* dstp = ei + E;
        hipMemsetAsync(deg, 0, (size_t)N * sizeof(int), stream);
        k_count<<<(E + 255) / 256, 256, 0, stream>>>(dstp, deg, E);
        k_scan<<<1, 1024, 0, stream>>>(deg, rowptr, N);
        hipMemcpyAsync(cursor, rowptr, (size_t)N * sizeof(int),
                       hipMemcpyDeviceToDevice, stream);
        k_fill<<<(E + 255) / 256, 256, 0, stream>>>(srcp, dstp, cursor, colbuf, E);
        k_aggregate<<<(N + 3) / 4, 256, 0, stream>>>(X, rowptr, colbuf, Aagg, N);
    };

    // Layer 1: H = relu(mean_agg(x) @ W1l^T + x @ W1r^T + b1)
    build_and_agg(ei1, E1, x);
    dim3 g1((N + BM - 1) / BM, DHID / BN);
    k_gemm_dual<<<g1, 256, 0, stream>>>(Aagg, W1l, x, W1r, b1, H, N, DIN, DHID, 1);

    // Layer 2: out = mean_agg(H) @ W2l^T + H @ W2r^T + b2
    build_and_agg(ei2, E2, H);
    dim3 g2((N + BM - 1) / BM, DOUT / BN);
    k_gemm_dual<<<g2, 256, 0, stream>>>(Aagg, W2l, H, W2r, b2, out, N, DHID, DOUT, 0);

    // log_softmax in place on d_out
    k_logsoftmax<<<(N + 3) / 4, 256, 0, stream>>>(out, N);
}

// Round 2
// 803.288 us; speedup vs baseline: 2.8289x; 2.8289x over previous
//
#include <hip/hip_runtime.h>
#include <math.h>

#define DIN  512
#define DHID 512
#define DOUT 256

typedef __attribute__((ext_vector_type(8))) short short8;
typedef __attribute__((ext_vector_type(4))) float f32x4;

__device__ __forceinline__ unsigned short f2bf(float f) {
    unsigned int u = __float_as_uint(f);
    u += 0x7fffu + ((u >> 16) & 1u);
    return (unsigned short)(u >> 16);
}

// ---------------------------------------------------------------------------
// fp32 -> bf16 conversion, 8 elems/thread
__global__ void k_f2bf(const float* __restrict__ in, unsigned short* __restrict__ out, int n8) {
    int i = blockIdx.x * blockDim.x + threadIdx.x;
    if (i >= n8) return;
    const float4* iv = (const float4*)in;
    float4 a = iv[2 * i], b = iv[2 * i + 1];
    uint4 o;
    o.x = (unsigned)f2bf(a.x) | ((unsigned)f2bf(a.y) << 16);
    o.y = (unsigned)f2bf(a.z) | ((unsigned)f2bf(a.w) << 16);
    o.z = (unsigned)f2bf(b.x) | ((unsigned)f2bf(b.y) << 16);
    o.w = (unsigned)f2bf(b.z) | ((unsigned)f2bf(b.w) << 16);
    ((uint4*)out)[i] = o;
}

// ---------------------------------------------------------------------------
// CSR build
__global__ void k_count(const int* __restrict__ dst, int* __restrict__ deg, int E) {
    int e = blockIdx.x * blockDim.x + threadIdx.x;
    if (e < E) atomicAdd(&deg[dst[e]], 1);
}

__global__ void k_scan(const int* __restrict__ deg, int* __restrict__ rowptr, int n) {
    __shared__ int sdata[1024];
    __shared__ int s_carry;
    int tid = threadIdx.x;
    if (tid == 0) s_carry = 0;
    __syncthreads();
    for (int base = 0; base < n; base += 1024) {
        int i = base + tid;
        int v = (i < n) ? deg[i] : 0;
        sdata[tid] = v;
        __syncthreads();
        for (int off = 1; off < 1024; off <<= 1) {
            int t = (tid >= off) ? sdata[tid - off] : 0;
            __syncthreads();
            sdata[tid] += t;
            __syncthreads();
        }
        int incl = sdata[tid];
        if (i < n) rowptr[i] = s_carry + (incl - v);
        __syncthreads();
        if (tid == 1023) s_carry += sdata[1023];
        __syncthreads();
    }
    if (tid == 0) rowptr[n] = s_carry;
}

__global__ void k_fill(const int* __restrict__ src, const int* __restrict__ dst,
                       int* __restrict__ cursor, int* __restrict__ col, int E) {
    int e = blockIdx.x * blockDim.x + threadIdx.x;
    if (e < E) {
        int p = atomicAdd(&cursor[dst[e]], 1);
        col[p] = src[e];
    }
}

// ---------------------------------------------------------------------------
// Mean aggregation over bf16 rows (D=512), fp32 accumulate, bf16 out.
// One wave per node; lane holds 8 elems (one uint4 = 16 B).
__global__ void k_aggregate_bf(const unsigned short* __restrict__ X,
                               const int* __restrict__ rowptr, const int* __restrict__ col,
                               unsigned short* __restrict__ A, int n) {
    int node = blockIdx.x * (blockDim.x >> 6) + (threadIdx.x >> 6);
    int lane = threadIdx.x & 63;
    if (node >= n) return;
    int beg = rowptr[node], end = rowptr[node + 1];
    float acc[8] = {};
    const uint4* Xv = (const uint4*)X;   // 512 bf16 = 64 uint4 per row
    for (int e = beg; e < end; ++e) {
        uint4 v = Xv[(size_t)col[e] * 64 + lane];
        unsigned int w[4] = {v.x, v.y, v.z, v.w};
#pragma unroll
        for (int q = 0; q < 4; ++q) {
            acc[2 * q]     += __uint_as_float(w[q] << 16);
            acc[2 * q + 1] += __uint_as_float(w[q] & 0xffff0000u);
        }
    }
    float inv = 1.0f / fmaxf((float)(end - beg), 1.0f);
    unsigned int r[4];
#pragma unroll
    for (int q = 0; q < 4; ++q)
        r[q] = (unsigned)f2bf(acc[2 * q] * inv) | ((unsigned)f2bf(acc[2 * q + 1] * inv) << 16);
    uint4 o; o.x = r[0]; o.y = r[1]; o.z = r[2]; o.w = r[3];
    ((uint4*)A)[(size_t)node * 64 + lane] = o;
}

// ---------------------------------------------------------------------------
// bf16 MFMA dual-GEMM: C = act(A1 @ W1^T + A2 @ W2^T + bias)
// A*: [M,K] bf16 row-major; W*: [NC,K] bf16 row-major; C: [M,NC] (OUT_T)
// 128x128 tile, BK=32, 256 threads (4 waves, each a 64x64 quadrant of 4x4
// 16x16x32 MFMA tiles). global_load_lds width-16 staging (m97 structure).
#define TM 128
#define TN 128
#define TK 32

template <int RELU, typename OUT_T>
__global__ __launch_bounds__(256)
void k_gemm_mfma(const unsigned short* __restrict__ A1, const unsigned short* __restrict__ W1,
                 const unsigned short* __restrict__ A2, const unsigned short* __restrict__ W2,
                 const float* __restrict__ bias, OUT_T* __restrict__ C,
                 int M, int K, int NC) {
    __shared__ __align__(16) unsigned short As[TM * TK];  // [row][k], k contiguous
    __shared__ __align__(16) unsigned short Bs[TN * TK];  // [n][k],  k contiguous
    const int t = threadIdx.x;
    const int lane = t & 63;
    const int w = t >> 6;
    const int wr = (w >> 1) * 64;
    const int wc = (w & 1) * 64;
    const int row0 = blockIdx.x * TM;
    const int col0 = blockIdx.y * TN;

    const int lm = lane & 15;            // fragment row/col within 16
    const int k8 = (lane >> 4) * 8;      // fragment k-offset (quad*8)

    f32x4 acc[4][4];
#pragma unroll
    for (int i = 0; i < 4; ++i)
#pragma unroll
        for (int j = 0; j < 4; ++j) acc[i][j] = (f32x4){0.f, 0.f, 0.f, 0.f};

    // staging: chunk c (16 B = 8 bf16) covers tile row c>>2, k-seg (c&3)*8.
    // LDS index c*8 == (c>>2)*TK + (c&3)*8 for TK=32. Thread t does c=t, t+256.
    const int ar = t >> 2;
    const int as = (t & 3) * 8;

    for (int p = 0; p < 2; ++p) {
        const unsigned short* Ain = p ? A2 : A1;
        const unsigned short* Win = p ? W2 : W1;
        for (int k0 = 0; k0 < K; k0 += TK) {
            int r1 = row0 + ar;      if (r1 >= M) r1 = M - 1;
            int r2 = row0 + ar + 64; if (r2 >= M) r2 = M - 1;
            const unsigned short* ga1 = Ain + (size_t)r1 * K + k0 + as;
            const unsigned short* ga2 = Ain + (size_t)r2 * K + k0 + as;
            const unsigned short* gb1 = Win + (size_t)(col0 + ar) * K + k0 + as;
            const unsigned short* gb2 = Win + (size_t)(col0 + ar + 64) * K + k0 + as;
            __builtin_amdgcn_global_load_lds(
                (const __attribute__((address_space(1))) unsigned int*)ga1,
                (__attribute__((address_space(3))) unsigned int*)&As[t * 8], 16, 0, 0);
            __builtin_amdgcn_global_load_lds(
                (const __attribute__((address_space(1))) unsigned int*)ga2,
                (__attribute__((address_space(3))) unsigned int*)&As[(t + 256) * 8], 16, 0, 0);
            __builtin_amdgcn_global_load_lds(
                (const __attribute__((address_space(1))) unsigned int*)gb1,
                (__attribute__((address_space(3))) unsigned int*)&Bs[t * 8], 16, 0, 0);
            __builtin_amdgcn_global_load_lds(
                (const __attribute__((address_space(1))) unsigned int*)gb2,
                (__attribute__((address_space(3))) unsigned int*)&Bs[(t + 256) * 8], 16, 0, 0);
            __syncthreads();

            short8 a[4], b[4];
#pragma unroll
            for (int i = 0; i < 4; ++i)
                a[i] = *(const short8*)&As[(wr + i * 16 + lm) * TK + k8];
#pragma unroll
            for (int j = 0; j < 4; ++j)
                b[j] = *(const short8*)&Bs[(wc + j * 16 + lm) * TK + k8];
#pragma unroll
            for (int i = 0; i < 4; ++i)
#pragma unroll
                for (int j = 0; j < 4; ++j)
                    acc[i][j] = __builtin_amdgcn_mfma_f32_16x16x32_bf16(a[i], b[j], acc[i][j], 0, 0, 0);
            __syncthreads();
        }
    }

    // epilogue: D row = quad*4 + reg, col = lane&15 (m89/m91-verified)
    const int qr = (lane >> 4) * 4;
#pragma unroll
    for (int i = 0; i < 4; ++i) {
#pragma unroll
        for (int r = 0; r < 4; ++r) {
            int gr = row0 + wr + i * 16 + qr + r;
            if (gr >= M) continue;
#pragma unroll
            for (int j = 0; j < 4; ++j) {
                int gc = col0 + wc + j * 16 + lm;
                float v = acc[i][j][r] + bias[gc];
                if (RELU) v = fmaxf(v, 0.f);
                if (sizeof(OUT_T) == 2)
                    ((unsigned short*)C)[(size_t)gr * NC + gc] = f2bf(v);
                else
                    ((float*)C)[(size_t)gr * NC + gc] = v;
            }
        }
    }
}

// ---------------------------------------------------------------------------
// Row-wise log_softmax over DOUT=256 columns, in place. One wave per row.
__global__ void k_logsoftmax(float* __restrict__ O, int M) {
    int row = blockIdx.x * (blockDim.x >> 6) + (threadIdx.x >> 6);
    int lane = threadIdx.x & 63;
    if (row >= M) return;
    float4* rp = (float4*)(O + (size_t)row * DOUT);
    float4 v = rp[lane];
    float mx = fmaxf(fmaxf(v.x, v.y), fmaxf(v.z, v.w));
#pragma unroll
    for (int off = 32; off > 0; off >>= 1) mx = fmaxf(mx, __shfl_xor(mx, off));
    float s = expf(v.x - mx) + expf(v.y - mx) + expf(v.z - mx) + expf(v.w - mx);
#pragma unroll
    for (int off = 32; off > 0; off >>= 1) s += __shfl_xor(s, off);
    float lse = mx + logf(s);
    v.x -= lse; v.y -= lse; v.z -= lse; v.w -= lse;
    rp[lane] = v;
}

// ---------------------------------------------------------------------------
extern "C" void kernel_launch(void* const* d_in, const int* in_sizes, int n_in,
                              void* d_out, int out_size, void* d_ws, size_t ws_size,
                              hipStream_t stream) {
    const float* x   = (const float*)d_in[0];
    const int*   ei1 = (const int*)d_in[1];
    const int*   ei2 = (const int*)d_in[2];
    const float* W1l = (const float*)d_in[3];
    const float* b1  = (const float*)d_in[4];
    const float* W1r = (const float*)d_in[5];
    const float* W2l = (const float*)d_in[6];
    const float* b2  = (const float*)d_in[7];
    const float* W2r = (const float*)d_in[8];
    float* out = (float*)d_out;

    const int N  = in_sizes[0] / DIN;
    const int E1 = in_sizes[1] / 2;
    const int E2 = in_sizes[2] / 2;

    // Workspace layout (bf16 arrays are 16B-aligned by construction)
    unsigned short* x_bf   = (unsigned short*)d_ws;            // N*512
    unsigned short* h_bf   = x_bf + (size_t)N * 512;           // N*512
    unsigned short* agg_bf = h_bf + (size_t)N * 512;           // N*512
    unsigned short* w1l_bf = agg_bf + (size_t)N * 512;         // 512*512
    unsigned short* w1r_bf = w1l_bf + 512 * 512;
    unsigned short* w2l_bf = w1r_bf + 512 * 512;               // 256*512
    unsigned short* w2r_bf = w2l_bf + 256 * 512;
    int* rowptr = (int*)(w2r_bf + 256 * 512);                  // N+1
    int* cursor = rowptr + (N + 1);
    int* deg    = cursor + N;
    int* colbuf = deg + N;
    (void)ws_size; (void)n_in; (void)out_size;

    // dtype conversions
    {
        int n8 = N * 512 / 8;
        k_f2bf<<<(n8 + 255) / 256, 256, 0, stream>>>(x, x_bf, n8);
        int w8 = 512 * 512 / 8;
        k_f2bf<<<(w8 + 255) / 256, 256, 0, stream>>>(W1l, w1l_bf, w8);
        k_f2bf<<<(w8 + 255) / 256, 256, 0, stream>>>(W1r, w1r_bf, w8);
        int v8 = 256 * 512 / 8;
        k_f2bf<<<(v8 + 255) / 256, 256, 0, stream>>>(W2l, w2l_bf, v8);
        k_f2bf<<<(v8 + 255) / 256, 256, 0, stream>>>(W2r, w2r_bf, v8);
    }

    auto build_and_agg = [&](const int* ei, int E, const unsigned short* Xbf) {
        const int* srcp = ei;
        const int* dstp = ei + E;
        hipMemsetAsync(deg, 0, (size_t)N * sizeof(int), stream);
        k_count<<<(E + 255) / 256, 256, 0, stream>>>(dstp, deg, E);
        k_scan<<<1, 1024, 0, stream>>>(deg, rowptr, N);
        hipMemcpyAsync(cursor, rowptr, (size_t)N * sizeof(int),
                       hipMemcpyDeviceToDevice, stream);
        k_fill<<<(E + 255) / 256, 256, 0, stream>>>(srcp, dstp, cursor, colbuf, E);
        k_aggregate_bf<<<(N + 3) / 4, 256, 0, stream>>>(Xbf, rowptr, colbuf, agg_bf, N);
    };

    const int MB = (N + TM - 1) / TM;  // 391

    // Layer 1: H = relu(agg(x) @ W1l^T + x @ W1r^T + b1), bf16 out
    build_and_agg(ei1, E1, x_bf);
    k_gemm_mfma<1, unsigned short><<<dim3(MB, DHID / TN), 256, 0, stream>>>(
        agg_bf, w1l_bf, x_bf, w1r_bf, b1, h_bf, N, DIN, DHID);

    // Layer 2: out = agg(H) @ W2l^T + H @ W2r^T + b2, fp32 out
    build_and_agg(ei2, E2, h_bf);
    k_gemm_mfma<0, float><<<dim3(MB, DOUT / TN), 256, 0, stream>>>(
        agg_bf, w2l_bf, h_bf, w2r_bf, b2, out, N, DHID, DOUT);

    k_logsoftmax<<<(N + 3) / 4, 256, 0, stream>>>(out, N);
}

// Round 3
// 635.233 us; speedup vs baseline: 3.5773x; 1.2646x over previous
//
#include <hip/hip_runtime.h>
#include <math.h>

#define DIN  512
#define DHID 512
#define DOUT 256

typedef __attribute__((ext_vector_type(8))) short short8;
typedef __attribute__((ext_vector_type(4))) float f32x4;

__device__ __forceinline__ unsigned short f2bf(float f) {
    unsigned int u = __float_as_uint(f);
    u += 0x7fffu + ((u >> 16) & 1u);
    return (unsigned short)(u >> 16);
}

// ---------------------------------------------------------------------------
// fp32 -> bf16 conversion, 8 elems/thread
__global__ void k_f2bf(const float* __restrict__ in, unsigned short* __restrict__ out, int n8) {
    int i = blockIdx.x * blockDim.x + threadIdx.x;
    if (i >= n8) return;
    const float4* iv = (const float4*)in;
    float4 a = iv[2 * i], b = iv[2 * i + 1];
    uint4 o;
    o.x = (unsigned)f2bf(a.x) | ((unsigned)f2bf(a.y) << 16);
    o.y = (unsigned)f2bf(a.z) | ((unsigned)f2bf(a.w) << 16);
    o.z = (unsigned)f2bf(b.x) | ((unsigned)f2bf(b.y) << 16);
    o.w = (unsigned)f2bf(b.z) | ((unsigned)f2bf(b.w) << 16);
    ((uint4*)out)[i] = o;
}

// ---------------------------------------------------------------------------
// CSR build
__global__ void k_count(const int* __restrict__ dst, int* __restrict__ deg, int E) {
    int e = blockIdx.x * blockDim.x + threadIdx.x;
    if (e < E) atomicAdd(&deg[dst[e]], 1);
}

// 3-phase multi-block exclusive scan (N up to 256*256)
#define SCAN_B 256
__global__ void k_scan_partial(const int* __restrict__ deg, int* __restrict__ part, int n) {
    __shared__ int s[SCAN_B];
    int i = blockIdx.x * SCAN_B + threadIdx.x;
    s[threadIdx.x] = (i < n) ? deg[i] : 0;
    __syncthreads();
    for (int off = SCAN_B / 2; off > 0; off >>= 1) {
        if (threadIdx.x < off) s[threadIdx.x] += s[threadIdx.x + off];
        __syncthreads();
    }
    if (threadIdx.x == 0) part[blockIdx.x] = s[0];
}

// single block: exclusive-scan the per-block partials; write rowptr[n]=total
__global__ void k_scan_part2(int* __restrict__ part, int nb, int* __restrict__ rowptr, int n) {
    __shared__ int s[SCAN_B];
    int v = (threadIdx.x < nb) ? part[threadIdx.x] : 0;
    s[threadIdx.x] = v;
    __syncthreads();
    for (int off = 1; off < SCAN_B; off <<= 1) {
        int t = (threadIdx.x >= off) ? s[threadIdx.x - off] : 0;
        __syncthreads();
        s[threadIdx.x] += t;
        __syncthreads();
    }
    if (threadIdx.x < nb) part[threadIdx.x] = s[threadIdx.x] - v;  // exclusive
    if (threadIdx.x == SCAN_B - 1) rowptr[n] = s[SCAN_B - 1];
}

__global__ void k_scan_final(const int* __restrict__ deg, const int* __restrict__ part,
                             int* __restrict__ rowptr, int* __restrict__ cursor, int n) {
    __shared__ int s[SCAN_B];
    int i = blockIdx.x * SCAN_B + threadIdx.x;
    int v = (i < n) ? deg[i] : 0;
    s[threadIdx.x] = v;
    __syncthreads();
    for (int off = 1; off < SCAN_B; off <<= 1) {
        int t = (threadIdx.x >= off) ? s[threadIdx.x - off] : 0;
        __syncthreads();
        s[threadIdx.x] += t;
        __syncthreads();
    }
    if (i < n) {
        int ex = part[blockIdx.x] + s[threadIdx.x] - v;
        rowptr[i] = ex;
        cursor[i] = ex;
    }
}

__global__ void k_fill(const int* __restrict__ src, const int* __restrict__ dst,
                       int* __restrict__ cursor, int* __restrict__ col, int E) {
    int e = blockIdx.x * blockDim.x + threadIdx.x;
    if (e < E) {
        int p = atomicAdd(&cursor[dst[e]], 1);
        col[p] = src[e];
    }
}

// ---------------------------------------------------------------------------
// Mean aggregation over bf16 rows (D=512), fp32 accumulate, bf16 out.
// One wave per node; lane holds 8 elems (one uint4 = 16 B).
__global__ void k_aggregate_bf(const unsigned short* __restrict__ X,
                               const int* __restrict__ rowptr, const int* __restrict__ col,
                               unsigned short* __restrict__ A, int n) {
    int node = blockIdx.x * (blockDim.x >> 6) + (threadIdx.x >> 6);
    int lane = threadIdx.x & 63;
    if (node >= n) return;
    int beg = rowptr[node], end = rowptr[node + 1];
    float acc[8] = {};
    const uint4* Xv = (const uint4*)X;   // 512 bf16 = 64 uint4 per row
    for (int e = beg; e < end; ++e) {
        uint4 v = Xv[(size_t)col[e] * 64 + lane];
        unsigned int w[4] = {v.x, v.y, v.z, v.w};
#pragma unroll
        for (int q = 0; q < 4; ++q) {
            acc[2 * q]     += __uint_as_float(w[q] << 16);
            acc[2 * q + 1] += __uint_as_float(w[q] & 0xffff0000u);
        }
    }
    float inv = 1.0f / fmaxf((float)(end - beg), 1.0f);
    unsigned int r[4];
#pragma unroll
    for (int q = 0; q < 4; ++q)
        r[q] = (unsigned)f2bf(acc[2 * q] * inv) | ((unsigned)f2bf(acc[2 * q + 1] * inv) << 16);
    uint4 o; o.x = r[0]; o.y = r[1]; o.z = r[2]; o.w = r[3];
    ((uint4*)A)[(size_t)node * 64 + lane] = o;
}

// ---------------------------------------------------------------------------
// bf16 MFMA dual-GEMM: C = act(A1 @ W1^T + A2 @ W2^T + bias)
// Grid: (NC/TN, ceil(M/TM)) — column tiles vary FASTEST so consecutive
// blocks share one A row-tile (L2/L3 reuse; A fetched from HBM once).
#define TM 128
#define TN 128
#define TK 32

template <int RELU, typename OUT_T>
__global__ __launch_bounds__(256)
void k_gemm_mfma(const unsigned short* __restrict__ A1, const unsigned short* __restrict__ W1,
                 const unsigned short* __restrict__ A2, const unsigned short* __restrict__ W2,
                 const float* __restrict__ bias, OUT_T* __restrict__ C,
                 int M, int K, int NC) {
    __shared__ __align__(16) unsigned short As[TM * TK];  // [row][k], k contiguous
    __shared__ __align__(16) unsigned short Bs[TN * TK];  // [n][k],  k contiguous
    const int t = threadIdx.x;
    const int lane = t & 63;
    const int w = t >> 6;
    const int wr = (w >> 1) * 64;
    const int wc = (w & 1) * 64;
    const int row0 = blockIdx.y * TM;
    const int col0 = blockIdx.x * TN;

    const int lm = lane & 15;            // fragment row/col within 16
    const int k8 = (lane >> 4) * 8;      // fragment k-offset (quad*8)

    f32x4 acc[4][4];
#pragma unroll
    for (int i = 0; i < 4; ++i)
#pragma unroll
        for (int j = 0; j < 4; ++j) acc[i][j] = (f32x4){0.f, 0.f, 0.f, 0.f};

    const int ar = t >> 2;
    const int as = (t & 3) * 8;

    for (int p = 0; p < 2; ++p) {
        const unsigned short* Ain = p ? A2 : A1;
        const unsigned short* Win = p ? W2 : W1;
        for (int k0 = 0; k0 < K; k0 += TK) {
            int r1 = row0 + ar;      if (r1 >= M) r1 = M - 1;
            int r2 = row0 + ar + 64; if (r2 >= M) r2 = M - 1;
            const unsigned short* ga1 = Ain + (size_t)r1 * K + k0 + as;
            const unsigned short* ga2 = Ain + (size_t)r2 * K + k0 + as;
            const unsigned short* gb1 = Win + (size_t)(col0 + ar) * K + k0 + as;
            const unsigned short* gb2 = Win + (size_t)(col0 + ar + 64) * K + k0 + as;
            __builtin_amdgcn_global_load_lds(
                (const __attribute__((address_space(1))) unsigned int*)ga1,
                (__attribute__((address_space(3))) unsigned int*)&As[t * 8], 16, 0, 0);
            __builtin_amdgcn_global_load_lds(
                (const __attribute__((address_space(1))) unsigned int*)ga2,
                (__attribute__((address_space(3))) unsigned int*)&As[(t + 256) * 8], 16, 0, 0);
            __builtin_amdgcn_global_load_lds(
                (const __attribute__((address_space(1))) unsigned int*)gb1,
                (__attribute__((address_space(3))) unsigned int*)&Bs[t * 8], 16, 0, 0);
            __builtin_amdgcn_global_load_lds(
                (const __attribute__((address_space(1))) unsigned int*)gb2,
                (__attribute__((address_space(3))) unsigned int*)&Bs[(t + 256) * 8], 16, 0, 0);
            __syncthreads();

            short8 a[4], b[4];
#pragma unroll
            for (int i = 0; i < 4; ++i)
                a[i] = *(const short8*)&As[(wr + i * 16 + lm) * TK + k8];
#pragma unroll
            for (int j = 0; j < 4; ++j)
                b[j] = *(const short8*)&Bs[(wc + j * 16 + lm) * TK + k8];
#pragma unroll
            for (int i = 0; i < 4; ++i)
#pragma unroll
                for (int j = 0; j < 4; ++j)
                    acc[i][j] = __builtin_amdgcn_mfma_f32_16x16x32_bf16(a[i], b[j], acc[i][j], 0, 0, 0);
            __syncthreads();
        }
    }

    // epilogue: D row = quad*4 + reg, col = lane&15
    const int qr = (lane >> 4) * 4;
#pragma unroll
    for (int i = 0; i < 4; ++i) {
#pragma unroll
        for (int r = 0; r < 4; ++r) {
            int gr = row0 + wr + i * 16 + qr + r;
            if (gr >= M) continue;
#pragma unroll
            for (int j = 0; j < 4; ++j) {
                int gc = col0 + wc + j * 16 + lm;
                float v = acc[i][j][r] + bias[gc];
                if (RELU) v = fmaxf(v, 0.f);
                if (sizeof(OUT_T) == 2)
                    ((unsigned short*)C)[(size_t)gr * NC + gc] = f2bf(v);
                else
                    ((float*)C)[(size_t)gr * NC + gc] = v;
            }
        }
    }
}

// ---------------------------------------------------------------------------
// Row-wise log_softmax over DOUT=256 columns, in place. One wave per row.
__global__ void k_logsoftmax(float* __restrict__ O, int M) {
    int row = blockIdx.x * (blockDim.x >> 6) + (threadIdx.x >> 6);
    int lane = threadIdx.x & 63;
    if (row >= M) return;
    float4* rp = (float4*)(O + (size_t)row * DOUT);
    float4 v = rp[lane];
    float mx = fmaxf(fmaxf(v.x, v.y), fmaxf(v.z, v.w));
#pragma unroll
    for (int off = 32; off > 0; off >>= 1) mx = fmaxf(mx, __shfl_xor(mx, off));
    float s = expf(v.x - mx) + expf(v.y - mx) + expf(v.z - mx) + expf(v.w - mx);
#pragma unroll
    for (int off = 32; off > 0; off >>= 1) s += __shfl_xor(s, off);
    float lse = mx + logf(s);
    v.x -= lse; v.y -= lse; v.z -= lse; v.w -= lse;
    rp[lane] = v;
}

// ---------------------------------------------------------------------------
extern "C" void kernel_launch(void* const* d_in, const int* in_sizes, int n_in,
                              void* d_out, int out_size, void* d_ws, size_t ws_size,
                              hipStream_t stream) {
    const float* x   = (const float*)d_in[0];
    const int*   ei1 = (const int*)d_in[1];
    const int*   ei2 = (const int*)d_in[2];
    const float* W1l = (const float*)d_in[3];
    const float* b1  = (const float*)d_in[4];
    const float* W1r = (const float*)d_in[5];
    const float* W2l = (const float*)d_in[6];
    const float* b2  = (const float*)d_in[7];
    const float* W2r = (const float*)d_in[8];
    float* out = (float*)d_out;

    const int N  = in_sizes[0] / DIN;
    const int E1 = in_sizes[1] / 2;
    const int E2 = in_sizes[2] / 2;
    const int NB = (N + SCAN_B - 1) / SCAN_B;   // scan blocks (196 <= 256)

    // Workspace layout
    unsigned short* x_bf   = (unsigned short*)d_ws;            // N*512
    unsigned short* h_bf   = x_bf + (size_t)N * 512;           // N*512
    unsigned short* agg_bf = h_bf + (size_t)N * 512;           // N*512
    unsigned short* w1l_bf = agg_bf + (size_t)N * 512;         // 512*512
    unsigned short* w1r_bf = w1l_bf + 512 * 512;
    unsigned short* w2l_bf = w1r_bf + 512 * 512;               // 256*512
    unsigned short* w2r_bf = w2l_bf + 256 * 512;
    int* rowptr = (int*)(w2r_bf + 256 * 512);                  // N+1
    int* cursor = rowptr + (N + 1);
    int* deg    = cursor + N;
    int* part   = deg + N;                                     // NB (<=256)
    int* colbuf = part + 256;                                  // Emax
    (void)ws_size; (void)n_in; (void)out_size;

    // dtype conversions
    {
        int n8 = N * 512 / 8;
        k_f2bf<<<(n8 + 255) / 256, 256, 0, stream>>>(x, x_bf, n8);
        int w8 = 512 * 512 / 8;
        k_f2bf<<<(w8 + 255) / 256, 256, 0, stream>>>(W1l, w1l_bf, w8);
        k_f2bf<<<(w8 + 255) / 256, 256, 0, stream>>>(W1r, w1r_bf, w8);
        int v8 = 256 * 512 / 8;
        k_f2bf<<<(v8 + 255) / 256, 256, 0, stream>>>(W2l, w2l_bf, v8);
        k_f2bf<<<(v8 + 255) / 256, 256, 0, stream>>>(W2r, w2r_bf, v8);
    }

    auto build_and_agg = [&](const int* ei, int E, const unsigned short* Xbf) {
        const int* srcp = ei;
        const int* dstp = ei + E;
        hipMemsetAsync(deg, 0, (size_t)N * sizeof(int), stream);
        k_count<<<(E + 255) / 256, 256, 0, stream>>>(dstp, deg, E);
        k_scan_partial<<<NB, SCAN_B, 0, stream>>>(deg, part, N);
        k_scan_part2<<<1, SCAN_B, 0, stream>>>(part, NB, rowptr, N);
        k_scan_final<<<NB, SCAN_B, 0, stream>>>(deg, part, rowptr, cursor, N);
        k_fill<<<(E + 255) / 256, 256, 0, stream>>>(srcp, dstp, cursor, colbuf, E);
        k_aggregate_bf<<<(N + 3) / 4, 256, 0, stream>>>(Xbf, rowptr, colbuf, agg_bf, N);
    };

    const int MB = (N + TM - 1) / TM;  // 391

    // Layer 1: H = relu(agg(x) @ W1l^T + x @ W1r^T + b1), bf16 out
    build_and_agg(ei1, E1, x_bf);
    k_gemm_mfma<1, unsigned short><<<dim3(DHID / TN, MB), 256, 0, stream>>>(
        agg_bf, w1l_bf, x_bf, w1r_bf, b1, h_bf, N, DIN, DHID);

    // Layer 2: out = agg(H) @ W2l^T + H @ W2r^T + b2, fp32 out
    build_and_agg(ei2, E2, h_bf);
    k_gemm_mfma<0, float><<<dim3(DOUT / TN, MB), 256, 0, stream>>>(
        agg_bf, w2l_bf, h_bf, w2r_bf, b2, out, N, DHID, DOUT);

    k_logsoftmax<<<(N + 3) / 4, 256, 0, stream>>>(out, N);
}

// Round 4
// 594.825 us; speedup vs baseline: 3.8203x; 1.0679x over previous
//
#include <hip/hip_runtime.h>
#include <math.h>

#define DIN  512
#define DHID 512
#define DOUT 256

typedef __attribute__((ext_vector_type(8))) short short8;
typedef __attribute__((ext_vector_type(4))) float f32x4;

__device__ __forceinline__ unsigned short f2bf(float f) {
    unsigned int u = __float_as_uint(f);
    u += 0x7fffu + ((u >> 16) & 1u);
    return (unsigned short)(u >> 16);
}

// ---------------------------------------------------------------------------
// fp32 -> bf16 conversion, 8 elems/thread
__global__ void k_f2bf(const float* __restrict__ in, unsigned short* __restrict__ out, int n8) {
    int i = blockIdx.x * blockDim.x + threadIdx.x;
    if (i >= n8) return;
    const float4* iv = (const float4*)in;
    float4 a = iv[2 * i], b = iv[2 * i + 1];
    uint4 o;
    o.x = (unsigned)f2bf(a.x) | ((unsigned)f2bf(a.y) << 16);
    o.y = (unsigned)f2bf(a.z) | ((unsigned)f2bf(a.w) << 16);
    o.z = (unsigned)f2bf(b.x) | ((unsigned)f2bf(b.y) << 16);
    o.w = (unsigned)f2bf(b.z) | ((unsigned)f2bf(b.w) << 16);
    ((uint4*)out)[i] = o;
}

// ---------------------------------------------------------------------------
// CSR build
__global__ void k_count(const int* __restrict__ dst, int* __restrict__ deg, int E) {
    int e = blockIdx.x * blockDim.x + threadIdx.x;
    if (e < E) atomicAdd(&deg[dst[e]], 1);
}

#define SCAN_B 256
__global__ void k_scan_partial(const int* __restrict__ deg, int* __restrict__ part, int n) {
    __shared__ int s[SCAN_B];
    int i = blockIdx.x * SCAN_B + threadIdx.x;
    s[threadIdx.x] = (i < n) ? deg[i] : 0;
    __syncthreads();
    for (int off = SCAN_B / 2; off > 0; off >>= 1) {
        if (threadIdx.x < off) s[threadIdx.x] += s[threadIdx.x + off];
        __syncthreads();
    }
    if (threadIdx.x == 0) part[blockIdx.x] = s[0];
}

__global__ void k_scan_part2(int* __restrict__ part, int nb, int* __restrict__ rowptr, int n) {
    __shared__ int s[SCAN_B];
    int v = (threadIdx.x < nb) ? part[threadIdx.x] : 0;
    s[threadIdx.x] = v;
    __syncthreads();
    for (int off = 1; off < SCAN_B; off <<= 1) {
        int t = (threadIdx.x >= off) ? s[threadIdx.x - off] : 0;
        __syncthreads();
        s[threadIdx.x] += t;
        __syncthreads();
    }
    if (threadIdx.x < nb) part[threadIdx.x] = s[threadIdx.x] - v;  // exclusive
    if (threadIdx.x == SCAN_B - 1) rowptr[n] = s[SCAN_B - 1];
}

__global__ void k_scan_final(const int* __restrict__ deg, const int* __restrict__ part,
                             int* __restrict__ rowptr, int* __restrict__ cursor, int n) {
    __shared__ int s[SCAN_B];
    int i = blockIdx.x * SCAN_B + threadIdx.x;
    int v = (i < n) ? deg[i] : 0;
    s[threadIdx.x] = v;
    __syncthreads();
    for (int off = 1; off < SCAN_B; off <<= 1) {
        int t = (threadIdx.x >= off) ? s[threadIdx.x - off] : 0;
        __syncthreads();
        s[threadIdx.x] += t;
        __syncthreads();
    }
    if (i < n) {
        int ex = part[blockIdx.x] + s[threadIdx.x] - v;
        rowptr[i] = ex;
        cursor[i] = ex;
    }
}

__global__ void k_fill(const int* __restrict__ src, const int* __restrict__ dst,
                       int* __restrict__ cursor, int* __restrict__ col, int E) {
    int e = blockIdx.x * blockDim.x + threadIdx.x;
    if (e < E) {
        int p = atomicAdd(&cursor[dst[e]], 1);
        col[p] = src[e];
    }
}

// ---------------------------------------------------------------------------
// Mean aggregation over bf16 rows (D=512), fp32 accumulate, bf16 out.
__global__ void k_aggregate_bf(const unsigned short* __restrict__ X,
                               const int* __restrict__ rowptr, const int* __restrict__ col,
                               unsigned short* __restrict__ A, int n) {
    int node = blockIdx.x * (blockDim.x >> 6) + (threadIdx.x >> 6);
    int lane = threadIdx.x & 63;
    if (node >= n) return;
    int beg = rowptr[node], end = rowptr[node + 1];
    float acc[8] = {};
    const uint4* Xv = (const uint4*)X;
    for (int e = beg; e < end; ++e) {
        uint4 v = Xv[(size_t)col[e] * 64 + lane];
        unsigned int w[4] = {v.x, v.y, v.z, v.w};
#pragma unroll
        for (int q = 0; q < 4; ++q) {
            acc[2 * q]     += __uint_as_float(w[q] << 16);
            acc[2 * q + 1] += __uint_as_float(w[q] & 0xffff0000u);
        }
    }
    float inv = 1.0f / fmaxf((float)(end - beg), 1.0f);
    unsigned int r[4];
#pragma unroll
    for (int q = 0; q < 4; ++q)
        r[q] = (unsigned)f2bf(acc[2 * q] * inv) | ((unsigned)f2bf(acc[2 * q + 1] * inv) << 16);
    uint4 o; o.x = r[0]; o.y = r[1]; o.z = r[2]; o.w = r[3];
    ((uint4*)A)[(size_t)node * 64 + lane] = o;
}

// ---------------------------------------------------------------------------
// bf16 MFMA dual-GEMM: C = act(A1 @ W1^T + A2 @ W2^T + bias)
// 1D grid with XCD-aware swizzle: id = 8*(g*NCT + c) + x, row_tile = 8g + x,
// col_tile = c. All NCT column-tiles of a row-tile share id%8 (same XCD on
// round-robin dispatch) AND are temporally adjacent -> A-tile enters exactly
// one L2, once. Heuristic only: wrong mapping costs speed, not correctness.
#define TM 128
#define TN 128
#define TK 32

template <int RELU, int NCT, typename OUT_T>
__global__ __launch_bounds__(256, 3)
void k_gemm_mfma(const unsigned short* __restrict__ A1, const unsigned short* __restrict__ W1,
                 const unsigned short* __restrict__ A2, const unsigned short* __restrict__ W2,
                 const float* __restrict__ bias, OUT_T* __restrict__ C,
                 int M, int K, int NC) {
    __shared__ __align__(16) unsigned short As[TM * TK];  // [row][k], k contiguous
    __shared__ __align__(16) unsigned short Bs[TN * TK];  // [n][k],  k contiguous
    const int id = blockIdx.x;
    const int xcd = id & 7;
    const int s = id >> 3;
    const int row0 = ((s / NCT) * 8 + xcd) * TM;
    const int col0 = (s % NCT) * TN;
    if (row0 >= M) return;

    const int t = threadIdx.x;
    const int lane = t & 63;
    const int w = t >> 6;
    const int wr = (w >> 1) * 64;
    const int wc = (w & 1) * 64;

    const int lm = lane & 15;            // fragment row/col within 16
    const int k8 = (lane >> 4) * 8;      // fragment k-offset (quad*8)

    f32x4 acc[4][4];
#pragma unroll
    for (int i = 0; i < 4; ++i)
#pragma unroll
        for (int j = 0; j < 4; ++j) acc[i][j] = (f32x4){0.f, 0.f, 0.f, 0.f};

    const int ar = t >> 2;
    const int as = (t & 3) * 8;

    for (int p = 0; p < 2; ++p) {
        const unsigned short* Ain = p ? A2 : A1;
        const unsigned short* Win = p ? W2 : W1;
        for (int k0 = 0; k0 < K; k0 += TK) {
            int r1 = row0 + ar;      if (r1 >= M) r1 = M - 1;
            int r2 = row0 + ar + 64; if (r2 >= M) r2 = M - 1;
            const unsigned short* ga1 = Ain + (size_t)r1 * K + k0 + as;
            const unsigned short* ga2 = Ain + (size_t)r2 * K + k0 + as;
            const unsigned short* gb1 = Win + (size_t)(col0 + ar) * K + k0 + as;
            const unsigned short* gb2 = Win + (size_t)(col0 + ar + 64) * K + k0 + as;
            __builtin_amdgcn_global_load_lds(
                (const __attribute__((address_space(1))) unsigned int*)ga1,
                (__attribute__((address_space(3))) unsigned int*)&As[t * 8], 16, 0, 0);
            __builtin_amdgcn_global_load_lds(
                (const __attribute__((address_space(1))) unsigned int*)ga2,
                (__attribute__((address_space(3))) unsigned int*)&As[(t + 256) * 8], 16, 0, 0);
            __builtin_amdgcn_global_load_lds(
                (const __attribute__((address_space(1))) unsigned int*)gb1,
                (__attribute__((address_space(3))) unsigned int*)&Bs[t * 8], 16, 0, 0);
            __builtin_amdgcn_global_load_lds(
                (const __attribute__((address_space(1))) unsigned int*)gb2,
                (__attribute__((address_space(3))) unsigned int*)&Bs[(t + 256) * 8], 16, 0, 0);
            __syncthreads();

            short8 a[4], b[4];
#pragma unroll
            for (int i = 0; i < 4; ++i)
                a[i] = *(const short8*)&As[(wr + i * 16 + lm) * TK + k8];
#pragma unroll
            for (int j = 0; j < 4; ++j)
                b[j] = *(const short8*)&Bs[(wc + j * 16 + lm) * TK + k8];
#pragma unroll
            for (int i = 0; i < 4; ++i)
#pragma unroll
                for (int j = 0; j < 4; ++j)
                    acc[i][j] = __builtin_amdgcn_mfma_f32_16x16x32_bf16(a[i], b[j], acc[i][j], 0, 0, 0);
            __syncthreads();
        }
    }

    // epilogue: D row = quad*4 + reg, col = lane&15
    const int qr = (lane >> 4) * 4;
#pragma unroll
    for (int i = 0; i < 4; ++i) {
#pragma unroll
        for (int r = 0; r < 4; ++r) {
            int gr = row0 + wr + i * 16 + qr + r;
            if (gr >= M) continue;
#pragma unroll
            for (int j = 0; j < 4; ++j) {
                int gc = col0 + wc + j * 16 + lm;
                float v = acc[i][j][r] + bias[gc];
                if (RELU) v = fmaxf(v, 0.f);
                if (sizeof(OUT_T) == 2)
                    ((unsigned short*)C)[(size_t)gr * NC + gc] = f2bf(v);
                else
                    ((float*)C)[(size_t)gr * NC + gc] = v;
            }
        }
    }
}

// ---------------------------------------------------------------------------
// Row-wise log_softmax over DOUT=256 columns, in place. One wave per row.
__global__ void k_logsoftmax(float* __restrict__ O, int M) {
    int row = blockIdx.x * (blockDim.x >> 6) + (threadIdx.x >> 6);
    int lane = threadIdx.x & 63;
    if (row >= M) return;
    float4* rp = (float4*)(O + (size_t)row * DOUT);
    float4 v = rp[lane];
    float mx = fmaxf(fmaxf(v.x, v.y), fmaxf(v.z, v.w));
#pragma unroll
    for (int off = 32; off > 0; off >>= 1) mx = fmaxf(mx, __shfl_xor(mx, off));
    float s = expf(v.x - mx) + expf(v.y - mx) + expf(v.z - mx) + expf(v.w - mx);
#pragma unroll
    for (int off = 32; off > 0; off >>= 1) s += __shfl_xor(s, off);
    float lse = mx + logf(s);
    v.x -= lse; v.y -= lse; v.z -= lse; v.w -= lse;
    rp[lane] = v;
}

// ---------------------------------------------------------------------------
extern "C" void kernel_launch(void* const* d_in, const int* in_sizes, int n_in,
                              void* d_out, int out_size, void* d_ws, size_t ws_size,
                              hipStream_t stream) {
    const float* x   = (const float*)d_in[0];
    const int*   ei1 = (const int*)d_in[1];
    const int*   ei2 = (const int*)d_in[2];
    const float* W1l = (const float*)d_in[3];
    const float* b1  = (const float*)d_in[4];
    const float* W1r = (const float*)d_in[5];
    const float* W2l = (const float*)d_in[6];
    const float* b2  = (const float*)d_in[7];
    const float* W2r = (const float*)d_in[8];
    float* out = (float*)d_out;

    const int N  = in_sizes[0] / DIN;
    const int E1 = in_sizes[1] / 2;
    const int E2 = in_sizes[2] / 2;
    const int NB = (N + SCAN_B - 1) / SCAN_B;

    // Workspace layout
    unsigned short* x_bf   = (unsigned short*)d_ws;            // N*512
    unsigned short* h_bf   = x_bf + (size_t)N * 512;           // N*512
    unsigned short* agg_bf = h_bf + (size_t)N * 512;           // N*512
    unsigned short* w1l_bf = agg_bf + (size_t)N * 512;         // 512*512
    unsigned short* w1r_bf = w1l_bf + 512 * 512;
    unsigned short* w2l_bf = w1r_bf + 512 * 512;               // 256*512
    unsigned short* w2r_bf = w2l_bf + 256 * 512;
    int* rowptr = (int*)(w2r_bf + 256 * 512);                  // N+1
    int* cursor = rowptr + (N + 1);
    int* deg    = cursor + N;
    int* part   = deg + N;                                     // <=256
    int* colbuf = part + 256;                                  // Emax
    (void)ws_size; (void)n_in; (void)out_size;

    // dtype conversions
    {
        int n8 = N * 512 / 8;
        k_f2bf<<<(n8 + 255) / 256, 256, 0, stream>>>(x, x_bf, n8);
        int w8 = 512 * 512 / 8;
        k_f2bf<<<(w8 + 255) / 256, 256, 0, stream>>>(W1l, w1l_bf, w8);
        k_f2bf<<<(w8 + 255) / 256, 256, 0, stream>>>(W1r, w1r_bf, w8);
        int v8 = 256 * 512 / 8;
        k_f2bf<<<(v8 + 255) / 256, 256, 0, stream>>>(W2l, w2l_bf, v8);
        k_f2bf<<<(v8 + 255) / 256, 256, 0, stream>>>(W2r, w2r_bf, v8);
    }

    auto build_and_agg = [&](const int* ei, int E, const unsigned short* Xbf) {
        const int* srcp = ei;
        const int* dstp = ei + E;
        hipMemsetAsync(deg, 0, (size_t)N * sizeof(int), stream);
        k_count<<<(E + 255) / 256, 256, 0, stream>>>(dstp, deg, E);
        k_scan_partial<<<NB, SCAN_B, 0, stream>>>(deg, part, N);
        k_scan_part2<<<1, SCAN_B, 0, stream>>>(part, NB, rowptr, N);
        k_scan_final<<<NB, SCAN_B, 0, stream>>>(deg, part, rowptr, cursor, N);
        k_fill<<<(E + 255) / 256, 256, 0, stream>>>(srcp, dstp, cursor, colbuf, E);
        k_aggregate_bf<<<(N + 3) / 4, 256, 0, stream>>>(Xbf, rowptr, colbuf, agg_bf, N);
    };

    const int MB = (N + TM - 1) / TM;            // 391 row tiles
    const int G8 = (MB + 7) / 8;                 // row-tile groups of 8 (49)

    // Layer 1: H = relu(agg(x) @ W1l^T + x @ W1r^T + b1), bf16 out
    build_and_agg(ei1, E1, x_bf);
    k_gemm_mfma<1, 4, unsigned short><<<G8 * 8 * 4, 256, 0, stream>>>(
        agg_bf, w1l_bf, x_bf, w1r_bf, b1, h_bf, N, DIN, DHID);

    // Layer 2: out = agg(H) @ W2l^T + H @ W2r^T + b2, fp32 out
    build_and_agg(ei2, E2, h_bf);
    k_gemm_mfma<0, 2, float><<<G8 * 8 * 2, 256, 0, stream>>>(
        agg_bf, w2l_bf, h_bf, w2r_bf, b2, out, N, DHID, DOUT);

    k_logsoftmax<<<(N + 3) / 4, 256, 0, stream>>>(out, N);
}

// Round 5
// 571.479 us; speedup vs baseline: 3.9763x; 1.0409x over previous
//
#include <hip/hip_runtime.h>
#include <math.h>

#define DIN  512
#define DHID 512
#define DOUT 256

typedef __attribute__((ext_vector_type(8))) short short8;
typedef __attribute__((ext_vector_type(4))) float f32x4;

__device__ __forceinline__ unsigned short f2bf(float f) {
    unsigned int u = __float_as_uint(f);
    u += 0x7fffu + ((u >> 16) & 1u);
    return (unsigned short)(u >> 16);
}
__device__ __forceinline__ float bflo(unsigned int w) { return __uint_as_float(w << 16); }
__device__ __forceinline__ float bfhi(unsigned int w) { return __uint_as_float(w & 0xffff0000u); }

// ---------------------------------------------------------------------------
__global__ void k_f2bf(const float* __restrict__ in, unsigned short* __restrict__ out, int n8) {
    int i = blockIdx.x * blockDim.x + threadIdx.x;
    if (i >= n8) return;
    const float4* iv = (const float4*)in;
    float4 a = iv[2 * i], b = iv[2 * i + 1];
    uint4 o;
    o.x = (unsigned)f2bf(a.x) | ((unsigned)f2bf(a.y) << 16);
    o.y = (unsigned)f2bf(a.z) | ((unsigned)f2bf(a.w) << 16);
    o.z = (unsigned)f2bf(b.x) | ((unsigned)f2bf(b.y) << 16);
    o.w = (unsigned)f2bf(b.z) | ((unsigned)f2bf(b.w) << 16);
    ((uint4*)out)[i] = o;
}

// ---------------------------------------------------------------------------
// CSR build
__global__ void k_count(const int* __restrict__ dst, int* __restrict__ deg, int E) {
    int e = blockIdx.x * blockDim.x + threadIdx.x;
    if (e < E) atomicAdd(&deg[dst[e]], 1);
}

#define SCAN_B 256
__global__ void k_scan_partial(const int* __restrict__ deg, int* __restrict__ part, int n) {
    __shared__ int s[SCAN_B];
    int i = blockIdx.x * SCAN_B + threadIdx.x;
    s[threadIdx.x] = (i < n) ? deg[i] : 0;
    __syncthreads();
    for (int off = SCAN_B / 2; off > 0; off >>= 1) {
        if (threadIdx.x < off) s[threadIdx.x] += s[threadIdx.x + off];
        __syncthreads();
    }
    if (threadIdx.x == 0) part[blockIdx.x] = s[0];
}

__global__ void k_scan_part2(int* __restrict__ part, int nb, int* __restrict__ rowptr, int n) {
    __shared__ int s[SCAN_B];
    int v = (threadIdx.x < nb) ? part[threadIdx.x] : 0;
    s[threadIdx.x] = v;
    __syncthreads();
    for (int off = 1; off < SCAN_B; off <<= 1) {
        int t = (threadIdx.x >= off) ? s[threadIdx.x - off] : 0;
        __syncthreads();
        s[threadIdx.x] += t;
        __syncthreads();
    }
    if (threadIdx.x < nb) part[threadIdx.x] = s[threadIdx.x] - v;  // exclusive
    if (threadIdx.x == SCAN_B - 1) rowptr[n] = s[SCAN_B - 1];
}

__global__ void k_scan_final(const int* __restrict__ deg, const int* __restrict__ part,
                             int* __restrict__ rowptr, int* __restrict__ cursor, int n) {
    __shared__ int s[SCAN_B];
    int i = blockIdx.x * SCAN_B + threadIdx.x;
    int v = (i < n) ? deg[i] : 0;
    s[threadIdx.x] = v;
    __syncthreads();
    for (int off = 1; off < SCAN_B; off <<= 1) {
        int t = (threadIdx.x >= off) ? s[threadIdx.x - off] : 0;
        __syncthreads();
        s[threadIdx.x] += t;
        __syncthreads();
    }
    if (i < n) {
        int ex = part[blockIdx.x] + s[threadIdx.x] - v;
        rowptr[i] = ex;
        cursor[i] = ex;
    }
}

__global__ void k_fill(const int* __restrict__ src, const int* __restrict__ dst,
                       int* __restrict__ cursor, int* __restrict__ col, int E) {
    int e = blockIdx.x * blockDim.x + threadIdx.x;
    if (e < E) {
        int p = atomicAdd(&cursor[dst[e]], 1);
        col[p] = src[e];
    }
}

// ---------------------------------------------------------------------------
// bf16 MFMA GEMM: C = A @ W^T   (A: [M,K] bf16, W: [NC,K] bf16, C: [M,NC] bf16)
// XCD-aware 1D swizzle (round-4 verified: FETCH 203->58 MB).
#define TM 128
#define TN 128
#define TK 32

template <int NCT>
__global__ __launch_bounds__(256, 3)
void k_gemm_mfma(const unsigned short* __restrict__ A, const unsigned short* __restrict__ W,
                 unsigned short* __restrict__ C, int M, int K, int NC) {
    __shared__ __align__(16) unsigned short As[TM * TK];
    __shared__ __align__(16) unsigned short Bs[TN * TK];
    const int id = blockIdx.x;
    const int xcd = id & 7;
    const int s = id >> 3;
    const int row0 = ((s / NCT) * 8 + xcd) * TM;
    const int col0 = (s % NCT) * TN;
    if (row0 >= M) return;

    const int t = threadIdx.x;
    const int lane = t & 63;
    const int w = t >> 6;
    const int wr = (w >> 1) * 64;
    const int wc = (w & 1) * 64;
    const int lm = lane & 15;
    const int k8 = (lane >> 4) * 8;

    f32x4 acc[4][4];
#pragma unroll
    for (int i = 0; i < 4; ++i)
#pragma unroll
        for (int j = 0; j < 4; ++j) acc[i][j] = (f32x4){0.f, 0.f, 0.f, 0.f};

    const int ar = t >> 2;
    const int as = (t & 3) * 8;

    for (int k0 = 0; k0 < K; k0 += TK) {
        int r1 = row0 + ar;      if (r1 >= M) r1 = M - 1;
        int r2 = row0 + ar + 64; if (r2 >= M) r2 = M - 1;
        const unsigned short* ga1 = A + (size_t)r1 * K + k0 + as;
        const unsigned short* ga2 = A + (size_t)r2 * K + k0 + as;
        const unsigned short* gb1 = W + (size_t)(col0 + ar) * K + k0 + as;
        const unsigned short* gb2 = W + (size_t)(col0 + ar + 64) * K + k0 + as;
        __builtin_amdgcn_global_load_lds(
            (const __attribute__((address_space(1))) unsigned int*)ga1,
            (__attribute__((address_space(3))) unsigned int*)&As[t * 8], 16, 0, 0);
        __builtin_amdgcn_global_load_lds(
            (const __attribute__((address_space(1))) unsigned int*)ga2,
            (__attribute__((address_space(3))) unsigned int*)&As[(t + 256) * 8], 16, 0, 0);
        __builtin_amdgcn_global_load_lds(
            (const __attribute__((address_space(1))) unsigned int*)gb1,
            (__attribute__((address_space(3))) unsigned int*)&Bs[t * 8], 16, 0, 0);
        __builtin_amdgcn_global_load_lds(
            (const __attribute__((address_space(1))) unsigned int*)gb2,
            (__attribute__((address_space(3))) unsigned int*)&Bs[(t + 256) * 8], 16, 0, 0);
        __syncthreads();

        short8 a[4], b[4];
#pragma unroll
        for (int i = 0; i < 4; ++i)
            a[i] = *(const short8*)&As[(wr + i * 16 + lm) * TK + k8];
#pragma unroll
        for (int j = 0; j < 4; ++j)
            b[j] = *(const short8*)&Bs[(wc + j * 16 + lm) * TK + k8];
#pragma unroll
        for (int i = 0; i < 4; ++i)
#pragma unroll
            for (int j = 0; j < 4; ++j)
                acc[i][j] = __builtin_amdgcn_mfma_f32_16x16x32_bf16(a[i], b[j], acc[i][j], 0, 0, 0);
        __syncthreads();
    }

    const int qr = (lane >> 4) * 4;
#pragma unroll
    for (int i = 0; i < 4; ++i) {
#pragma unroll
        for (int r = 0; r < 4; ++r) {
            int gr = row0 + wr + i * 16 + qr + r;
            if (gr >= M) continue;
#pragma unroll
            for (int j = 0; j < 4; ++j) {
                int gc = col0 + wc + j * 16 + lm;
                C[(size_t)gr * NC + gc] = f2bf(acc[i][j][r]);
            }
        }
    }
}

// ---------------------------------------------------------------------------
// Layer-1 fused epilogue: h[i] = relu( mean_j C1l[j] + C1r[i] + b1 ), bf16 out.
// C1 rows: [y_l(512 bf16) | y_r(512 bf16)] = 128 uint4. One wave per node,
// lane covers dims 8*lane..8*lane+7 (one uint4).
__global__ void k_agg_relu(const unsigned short* __restrict__ C1,
                           const int* __restrict__ rowptr, const int* __restrict__ col,
                           const float* __restrict__ b1, unsigned short* __restrict__ H, int n) {
    int node = blockIdx.x * (blockDim.x >> 6) + (threadIdx.x >> 6);
    int lane = threadIdx.x & 63;
    if (node >= n) return;
    int beg = rowptr[node], end = rowptr[node + 1];
    float acc[8] = {};
    const uint4* Cv = (const uint4*)C1;   // row stride 128 uint4
    for (int e = beg; e < end; ++e) {
        uint4 v = Cv[(size_t)col[e] * 128 + lane];
        unsigned int wv[4] = {v.x, v.y, v.z, v.w};
#pragma unroll
        for (int q = 0; q < 4; ++q) {
            acc[2 * q]     += bflo(wv[q]);
            acc[2 * q + 1] += bfhi(wv[q]);
        }
    }
    float inv = 1.0f / fmaxf((float)(end - beg), 1.0f);
    uint4 yr = Cv[(size_t)node * 128 + 64 + lane];
    unsigned int wr[4] = {yr.x, yr.y, yr.z, yr.w};
    float4 bv0 = ((const float4*)b1)[2 * lane];
    float4 bv1 = ((const float4*)b1)[2 * lane + 1];
    float bb[8] = {bv0.x, bv0.y, bv0.z, bv0.w, bv1.x, bv1.y, bv1.z, bv1.w};
    unsigned int r[4];
#pragma unroll
    for (int q = 0; q < 4; ++q) {
        float v0 = fmaxf(acc[2 * q] * inv     + bflo(wr[q]) + bb[2 * q],     0.f);
        float v1 = fmaxf(acc[2 * q + 1] * inv + bfhi(wr[q]) + bb[2 * q + 1], 0.f);
        r[q] = (unsigned)f2bf(v0) | ((unsigned)f2bf(v1) << 16);
    }
    uint4 o; o.x = r[0]; o.y = r[1]; o.z = r[2]; o.w = r[3];
    ((uint4*)H)[(size_t)node * 64 + lane] = o;
}

// ---------------------------------------------------------------------------
// Layer-2 fused epilogue: out[i] = log_softmax( mean_j C2l[j] + C2r[i] + b2 ).
// C2 rows: [y_l(256 bf16) | y_r(256 bf16)] = 128 uint2. One wave per node,
// lane covers dims 4*lane..4*lane+3 (one uint2). Output fp32.
__global__ void k_agg_lsm(const unsigned short* __restrict__ C2,
                          const int* __restrict__ rowptr, const int* __restrict__ col,
                          const float* __restrict__ b2, float* __restrict__ O, int n) {
    int node = blockIdx.x * (blockDim.x >> 6) + (threadIdx.x >> 6);
    int lane = threadIdx.x & 63;
    if (node >= n) return;
    int beg = rowptr[node], end = rowptr[node + 1];
    float acc[4] = {};
    const uint2* Cv = (const uint2*)C2;   // row stride 128 uint2
    for (int e = beg; e < end; ++e) {
        uint2 v = Cv[(size_t)col[e] * 128 + lane];
        acc[0] += bflo(v.x); acc[1] += bfhi(v.x);
        acc[2] += bflo(v.y); acc[3] += bfhi(v.y);
    }
    float inv = 1.0f / fmaxf((float)(end - beg), 1.0f);
    uint2 yr = Cv[(size_t)node * 128 + 64 + lane];
    float4 bv = ((const float4*)b2)[lane];
    float val[4];
    val[0] = acc[0] * inv + bflo(yr.x) + bv.x;
    val[1] = acc[1] * inv + bfhi(yr.x) + bv.y;
    val[2] = acc[2] * inv + bflo(yr.y) + bv.z;
    val[3] = acc[3] * inv + bfhi(yr.y) + bv.w;
    float mx = fmaxf(fmaxf(val[0], val[1]), fmaxf(val[2], val[3]));
#pragma unroll
    for (int off = 32; off > 0; off >>= 1) mx = fmaxf(mx, __shfl_xor(mx, off));
    float s = expf(val[0] - mx) + expf(val[1] - mx) + expf(val[2] - mx) + expf(val[3] - mx);
#pragma unroll
    for (int off = 32; off > 0; off >>= 1) s += __shfl_xor(s, off);
    float lse = mx + logf(s);
    float4 o = make_float4(val[0] - lse, val[1] - lse, val[2] - lse, val[3] - lse);
    ((float4*)O)[(size_t)node * 64 + lane] = o;
}

// ---------------------------------------------------------------------------
extern "C" void kernel_launch(void* const* d_in, const int* in_sizes, int n_in,
                              void* d_out, int out_size, void* d_ws, size_t ws_size,
                              hipStream_t stream) {
    const float* x   = (const float*)d_in[0];
    const int*   ei1 = (const int*)d_in[1];
    const int*   ei2 = (const int*)d_in[2];
    const float* W1l = (const float*)d_in[3];
    const float* b1  = (const float*)d_in[4];
    const float* W1r = (const float*)d_in[5];
    const float* W2l = (const float*)d_in[6];
    const float* b2  = (const float*)d_in[7];
    const float* W2r = (const float*)d_in[8];
    float* out = (float*)d_out;

    const int N  = in_sizes[0] / DIN;
    const int E1 = in_sizes[1] / 2;
    const int E2 = in_sizes[2] / 2;
    const int NB = (N + SCAN_B - 1) / SCAN_B;

    // Workspace layout
    unsigned short* x_bf = (unsigned short*)d_ws;              // N*512
    unsigned short* h_bf = x_bf + (size_t)N * 512;             // N*512
    unsigned short* c1   = h_bf + (size_t)N * 512;             // N*1024 (c2 aliases)
    unsigned short* c2   = c1;                                  // N*512
    unsigned short* w1_bf = c1 + (size_t)N * 1024;             // [W1l;W1r] 1024x512
    unsigned short* w2_bf = w1_bf + 1024 * 512;                // [W2l;W2r] 512x512
    int* rowptr = (int*)(w2_bf + 512 * 512);                   // N+1
    int* cursor = rowptr + (N + 1);
    int* deg    = cursor + N;
    int* part   = deg + N;                                     // <=256
    int* colbuf = part + 256;                                  // Emax
    (void)ws_size; (void)n_in; (void)out_size;

    // dtype conversions (weights land concatenated: [Wl;Wr])
    {
        int n8 = N * 512 / 8;
        k_f2bf<<<(n8 + 255) / 256, 256, 0, stream>>>(x, x_bf, n8);
        int w8 = 512 * 512 / 8;
        k_f2bf<<<(w8 + 255) / 256, 256, 0, stream>>>(W1l, w1_bf, w8);
        k_f2bf<<<(w8 + 255) / 256, 256, 0, stream>>>(W1r, w1_bf + 512 * 512, w8);
        int v8 = 256 * 512 / 8;
        k_f2bf<<<(v8 + 255) / 256, 256, 0, stream>>>(W2l, w2_bf, v8);
        k_f2bf<<<(v8 + 255) / 256, 256, 0, stream>>>(W2r, w2_bf + 256 * 512, v8);
    }

    auto build_csr = [&](const int* ei, int E) {
        const int* srcp = ei;
        const int* dstp = ei + E;
        hipMemsetAsync(deg, 0, (size_t)N * sizeof(int), stream);
        k_count<<<(E + 255) / 256, 256, 0, stream>>>(dstp, deg, E);
        k_scan_partial<<<NB, SCAN_B, 0, stream>>>(deg, part, N);
        k_scan_part2<<<1, SCAN_B, 0, stream>>>(part, NB, rowptr, N);
        k_scan_final<<<NB, SCAN_B, 0, stream>>>(deg, part, rowptr, cursor, N);
        k_fill<<<(E + 255) / 256, 256, 0, stream>>>(srcp, dstp, cursor, colbuf, E);
    };

    const int MB = (N + TM - 1) / TM;            // 391 row tiles
    const int G8 = (MB + 7) / 8;                 // 49 groups of 8

    // Layer 1: C1 = x @ [W1l;W1r]^T  (N x 1024), then fused mean+bias+relu -> h
    build_csr(ei1, E1);
    k_gemm_mfma<8><<<G8 * 8 * 8, 256, 0, stream>>>(x_bf, w1_bf, c1, N, DIN, 1024);
    k_agg_relu<<<(N + 3) / 4, 256, 0, stream>>>(c1, rowptr, colbuf, b1, h_bf, N);

    // Layer 2: C2 = h @ [W2l;W2r]^T  (N x 512), then fused mean+bias+log_softmax
    build_csr(ei2, E2);
    k_gemm_mfma<4><<<G8 * 8 * 4, 256, 0, stream>>>(h_bf, w2_bf, c2, N, DHID, 512);
    k_agg_lsm<<<(N + 3) / 4, 256, 0, stream>>>(c2, rowptr, colbuf, b2, out, N);
}

// Round 6
// 546.723 us; speedup vs baseline: 4.1564x; 1.0453x over previous
//
#include <hip/hip_runtime.h>
#include <math.h>

#define DIN  512
#define DHID 512
#define DOUT 256

typedef __attribute__((ext_vector_type(8))) short short8;
typedef __attribute__((ext_vector_type(4))) float f32x4;

__device__ __forceinline__ unsigned short f2bf(float f) {
    unsigned int u = __float_as_uint(f);
    u += 0x7fffu + ((u >> 16) & 1u);
    return (unsigned short)(u >> 16);
}
__device__ __forceinline__ float bflo(unsigned int w) { return __uint_as_float(w << 16); }
__device__ __forceinline__ float bfhi(unsigned int w) { return __uint_as_float(w & 0xffff0000u); }

// ---------------------------------------------------------------------------
__global__ void k_f2bf(const float* __restrict__ in, unsigned short* __restrict__ out, int n8) {
    int i = blockIdx.x * blockDim.x + threadIdx.x;
    if (i >= n8) return;
    const float4* iv = (const float4*)in;
    float4 a = iv[2 * i], b = iv[2 * i + 1];
    uint4 o;
    o.x = (unsigned)f2bf(a.x) | ((unsigned)f2bf(a.y) << 16);
    o.y = (unsigned)f2bf(a.z) | ((unsigned)f2bf(a.w) << 16);
    o.z = (unsigned)f2bf(b.x) | ((unsigned)f2bf(b.y) << 16);
    o.w = (unsigned)f2bf(b.z) | ((unsigned)f2bf(b.w) << 16);
    ((uint4*)out)[i] = o;
}

// ---------------------------------------------------------------------------
// CSR build
__global__ void k_count(const int* __restrict__ dst, int* __restrict__ deg, int E) {
    int e = blockIdx.x * blockDim.x + threadIdx.x;
    if (e < E) atomicAdd(&deg[dst[e]], 1);
}

#define SCAN_B 256
__global__ void k_scan_partial(const int* __restrict__ deg, int* __restrict__ part, int n) {
    __shared__ int s[SCAN_B];
    int i = blockIdx.x * SCAN_B + threadIdx.x;
    s[threadIdx.x] = (i < n) ? deg[i] : 0;
    __syncthreads();
    for (int off = SCAN_B / 2; off > 0; off >>= 1) {
        if (threadIdx.x < off) s[threadIdx.x] += s[threadIdx.x + off];
        __syncthreads();
    }
    if (threadIdx.x == 0) part[blockIdx.x] = s[0];
}

__global__ void k_scan_part2(int* __restrict__ part, int nb, int* __restrict__ rowptr, int n) {
    __shared__ int s[SCAN_B];
    int v = (threadIdx.x < nb) ? part[threadIdx.x] : 0;
    s[threadIdx.x] = v;
    __syncthreads();
    for (int off = 1; off < SCAN_B; off <<= 1) {
        int t = (threadIdx.x >= off) ? s[threadIdx.x - off] : 0;
        __syncthreads();
        s[threadIdx.x] += t;
        __syncthreads();
    }
    if (threadIdx.x < nb) part[threadIdx.x] = s[threadIdx.x] - v;  // exclusive
    if (threadIdx.x == SCAN_B - 1) rowptr[n] = s[SCAN_B - 1];
}

__global__ void k_scan_final(const int* __restrict__ deg, const int* __restrict__ part,
                             int* __restrict__ rowptr, int* __restrict__ cursor, int n) {
    __shared__ int s[SCAN_B];
    int i = blockIdx.x * SCAN_B + threadIdx.x;
    int v = (i < n) ? deg[i] : 0;
    s[threadIdx.x] = v;
    __syncthreads();
    for (int off = 1; off < SCAN_B; off <<= 1) {
        int t = (threadIdx.x >= off) ? s[threadIdx.x - off] : 0;
        __syncthreads();
        s[threadIdx.x] += t;
        __syncthreads();
    }
    if (i < n) {
        int ex = part[blockIdx.x] + s[threadIdx.x] - v;
        rowptr[i] = ex;
        cursor[i] = ex;
    }
}

__global__ void k_fill(const int* __restrict__ src, const int* __restrict__ dst,
                       int* __restrict__ cursor, int* __restrict__ col, int E) {
    int e = blockIdx.x * blockDim.x + threadIdx.x;
    if (e < E) {
        int p = atomicAdd(&cursor[dst[e]], 1);
        col[p] = src[e];
    }
}

// ---------------------------------------------------------------------------
// bf16 MFMA GEMM: C = A @ W^T   (A: [M,K] bf16, W: [NC,K] bf16, C: [M,NC] bf16)
// XCD-aware 1D swizzle (round-4 verified: FETCH 203->58 MB).
#define TM 128
#define TN 128
#define TK 32

template <int NCT>
__global__ __launch_bounds__(256, 3)
void k_gemm_mfma(const unsigned short* __restrict__ A, const unsigned short* __restrict__ W,
                 unsigned short* __restrict__ C, int M, int K, int NC) {
    __shared__ __align__(16) unsigned short As[TM * TK];
    __shared__ __align__(16) unsigned short Bs[TN * TK];
    const int id = blockIdx.x;
    const int xcd = id & 7;
    const int s = id >> 3;
    const int row0 = ((s / NCT) * 8 + xcd) * TM;
    const int col0 = (s % NCT) * TN;
    if (row0 >= M) return;

    const int t = threadIdx.x;
    const int lane = t & 63;
    const int w = t >> 6;
    const int wr = (w >> 1) * 64;
    const int wc = (w & 1) * 64;
    const int lm = lane & 15;
    const int k8 = (lane >> 4) * 8;

    f32x4 acc[4][4];
#pragma unroll
    for (int i = 0; i < 4; ++i)
#pragma unroll
        for (int j = 0; j < 4; ++j) acc[i][j] = (f32x4){0.f, 0.f, 0.f, 0.f};

    const int ar = t >> 2;
    const int as = (t & 3) * 8;

    for (int k0 = 0; k0 < K; k0 += TK) {
        int r1 = row0 + ar;      if (r1 >= M) r1 = M - 1;
        int r2 = row0 + ar + 64; if (r2 >= M) r2 = M - 1;
        const unsigned short* ga1 = A + (size_t)r1 * K + k0 + as;
        const unsigned short* ga2 = A + (size_t)r2 * K + k0 + as;
        const unsigned short* gb1 = W + (size_t)(col0 + ar) * K + k0 + as;
        const unsigned short* gb2 = W + (size_t)(col0 + ar + 64) * K + k0 + as;
        __builtin_amdgcn_global_load_lds(
            (const __attribute__((address_space(1))) unsigned int*)ga1,
            (__attribute__((address_space(3))) unsigned int*)&As[t * 8], 16, 0, 0);
        __builtin_amdgcn_global_load_lds(
            (const __attribute__((address_space(1))) unsigned int*)ga2,
            (__attribute__((address_space(3))) unsigned int*)&As[(t + 256) * 8], 16, 0, 0);
        __builtin_amdgcn_global_load_lds(
            (const __attribute__((address_space(1))) unsigned int*)gb1,
            (__attribute__((address_space(3))) unsigned int*)&Bs[t * 8], 16, 0, 0);
        __builtin_amdgcn_global_load_lds(
            (const __attribute__((address_space(1))) unsigned int*)gb2,
            (__attribute__((address_space(3))) unsigned int*)&Bs[(t + 256) * 8], 16, 0, 0);
        __syncthreads();

        short8 a[4], b[4];
#pragma unroll
        for (int i = 0; i < 4; ++i)
            a[i] = *(const short8*)&As[(wr + i * 16 + lm) * TK + k8];
#pragma unroll
        for (int j = 0; j < 4; ++j)
            b[j] = *(const short8*)&Bs[(wc + j * 16 + lm) * TK + k8];
#pragma unroll
        for (int i = 0; i < 4; ++i)
#pragma unroll
            for (int j = 0; j < 4; ++j)
                acc[i][j] = __builtin_amdgcn_mfma_f32_16x16x32_bf16(a[i], b[j], acc[i][j], 0, 0, 0);
        __syncthreads();
    }

    const int qr = (lane >> 4) * 4;
#pragma unroll
    for (int i = 0; i < 4; ++i) {
#pragma unroll
        for (int r = 0; r < 4; ++r) {
            int gr = row0 + wr + i * 16 + qr + r;
            if (gr >= M) continue;
#pragma unroll
            for (int j = 0; j < 4; ++j) {
                int gc = col0 + wc + j * 16 + lm;
                C[(size_t)gr * NC + gc] = f2bf(acc[i][j][r]);
            }
        }
    }
}

// ---------------------------------------------------------------------------
// Layer-1 fused epilogue: h[i] = relu( mean_j C1l[j] + C1r[i] + b1 ), bf16 out.
// C1 rows: [y_l(512 bf16) | y_r(512 bf16)] = 128 uint4. One wave per node,
// lane covers dims 8*lane..8*lane+7. Edge loop unrolled x4 for MLP (4
// independent 16B/lane gathers in flight — the loop was latency-bound).
__global__ void k_agg_relu(const unsigned short* __restrict__ C1,
                           const int* __restrict__ rowptr, const int* __restrict__ col,
                           const float* __restrict__ b1, unsigned short* __restrict__ H, int n) {
    int node = blockIdx.x * (blockDim.x >> 6) + (threadIdx.x >> 6);
    int lane = threadIdx.x & 63;
    if (node >= n) return;
    int beg = rowptr[node], end = rowptr[node + 1];
    float acc[8] = {};
    const uint4* Cv = (const uint4*)C1;   // row stride 128 uint4
    int e = beg;
    for (; e + 4 <= end; e += 4) {
        int c0 = col[e], c1 = col[e + 1], c2 = col[e + 2], c3 = col[e + 3];
        uint4 v0 = Cv[(size_t)c0 * 128 + lane];
        uint4 v1 = Cv[(size_t)c1 * 128 + lane];
        uint4 v2 = Cv[(size_t)c2 * 128 + lane];
        uint4 v3 = Cv[(size_t)c3 * 128 + lane];
        unsigned int w0[4] = {v0.x, v0.y, v0.z, v0.w};
        unsigned int w1[4] = {v1.x, v1.y, v1.z, v1.w};
        unsigned int w2[4] = {v2.x, v2.y, v2.z, v2.w};
        unsigned int w3[4] = {v3.x, v3.y, v3.z, v3.w};
#pragma unroll
        for (int q = 0; q < 4; ++q) {
            acc[2 * q]     += bflo(w0[q]) + bflo(w1[q]) + bflo(w2[q]) + bflo(w3[q]);
            acc[2 * q + 1] += bfhi(w0[q]) + bfhi(w1[q]) + bfhi(w2[q]) + bfhi(w3[q]);
        }
    }
    for (; e < end; ++e) {
        uint4 v = Cv[(size_t)col[e] * 128 + lane];
        unsigned int wv[4] = {v.x, v.y, v.z, v.w};
#pragma unroll
        for (int q = 0; q < 4; ++q) {
            acc[2 * q]     += bflo(wv[q]);
            acc[2 * q + 1] += bfhi(wv[q]);
        }
    }
    float inv = 1.0f / fmaxf((float)(end - beg), 1.0f);
    uint4 yr = Cv[(size_t)node * 128 + 64 + lane];
    unsigned int wr[4] = {yr.x, yr.y, yr.z, yr.w};
    float4 bv0 = ((const float4*)b1)[2 * lane];
    float4 bv1 = ((const float4*)b1)[2 * lane + 1];
    float bb[8] = {bv0.x, bv0.y, bv0.z, bv0.w, bv1.x, bv1.y, bv1.z, bv1.w};
    unsigned int r[4];
#pragma unroll
    for (int q = 0; q < 4; ++q) {
        float v0 = fmaxf(acc[2 * q] * inv     + bflo(wr[q]) + bb[2 * q],     0.f);
        float v1 = fmaxf(acc[2 * q + 1] * inv + bfhi(wr[q]) + bb[2 * q + 1], 0.f);
        r[q] = (unsigned)f2bf(v0) | ((unsigned)f2bf(v1) << 16);
    }
    uint4 o; o.x = r[0]; o.y = r[1]; o.z = r[2]; o.w = r[3];
    ((uint4*)H)[(size_t)node * 64 + lane] = o;
}

// ---------------------------------------------------------------------------
// Layer-2 fused epilogue: out[i] = log_softmax( mean_j C2l[j] + C2r[i] + b2 ).
// C2 rows: [y_l(256 bf16) | y_r(256 bf16)] = 128 uint2. Edge loop unrolled x4.
__global__ void k_agg_lsm(const unsigned short* __restrict__ C2,
                          const int* __restrict__ rowptr, const int* __restrict__ col,
                          const float* __restrict__ b2, float* __restrict__ O, int n) {
    int node = blockIdx.x * (blockDim.x >> 6) + (threadIdx.x >> 6);
    int lane = threadIdx.x & 63;
    if (node >= n) return;
    int beg = rowptr[node], end = rowptr[node + 1];
    float acc[4] = {};
    const uint2* Cv = (const uint2*)C2;   // row stride 128 uint2
    int e = beg;
    for (; e + 4 <= end; e += 4) {
        int c0 = col[e], c1 = col[e + 1], c2 = col[e + 2], c3 = col[e + 3];
        uint2 v0 = Cv[(size_t)c0 * 128 + lane];
        uint2 v1 = Cv[(size_t)c1 * 128 + lane];
        uint2 v2 = Cv[(size_t)c2 * 128 + lane];
        uint2 v3 = Cv[(size_t)c3 * 128 + lane];
        acc[0] += bflo(v0.x) + bflo(v1.x) + bflo(v2.x) + bflo(v3.x);
        acc[1] += bfhi(v0.x) + bfhi(v1.x) + bfhi(v2.x) + bfhi(v3.x);
        acc[2] += bflo(v0.y) + bflo(v1.y) + bflo(v2.y) + bflo(v3.y);
        acc[3] += bfhi(v0.y) + bfhi(v1.y) + bfhi(v2.y) + bfhi(v3.y);
    }
    for (; e < end; ++e) {
        uint2 v = Cv[(size_t)col[e] * 128 + lane];
        acc[0] += bflo(v.x); acc[1] += bfhi(v.x);
        acc[2] += bflo(v.y); acc[3] += bfhi(v.y);
    }
    float inv = 1.0f / fmaxf((float)(end - beg), 1.0f);
    uint2 yr = Cv[(size_t)node * 128 + 64 + lane];
    float4 bv = ((const float4*)b2)[lane];
    float val[4];
    val[0] = acc[0] * inv + bflo(yr.x) + bv.x;
    val[1] = acc[1] * inv + bfhi(yr.x) + bv.y;
    val[2] = acc[2] * inv + bflo(yr.y) + bv.z;
    val[3] = acc[3] * inv + bfhi(yr.y) + bv.w;
    float mx = fmaxf(fmaxf(val[0], val[1]), fmaxf(val[2], val[3]));
#pragma unroll
    for (int off = 32; off > 0; off >>= 1) mx = fmaxf(mx, __shfl_xor(mx, off));
    float s = expf(val[0] - mx) + expf(val[1] - mx) + expf(val[2] - mx) + expf(val[3] - mx);
#pragma unroll
    for (int off = 32; off > 0; off >>= 1) s += __shfl_xor(s, off);
    float lse = mx + logf(s);
    float4 o = make_float4(val[0] - lse, val[1] - lse, val[2] - lse, val[3] - lse);
    ((float4*)O)[(size_t)node * 64 + lane] = o;
}

// ---------------------------------------------------------------------------
extern "C" void kernel_launch(void* const* d_in, const int* in_sizes, int n_in,
                              void* d_out, int out_size, void* d_ws, size_t ws_size,
                              hipStream_t stream) {
    const float* x   = (const float*)d_in[0];
    const int*   ei1 = (const int*)d_in[1];
    const int*   ei2 = (const int*)d_in[2];
    const float* W1l = (const float*)d_in[3];
    const float* b1  = (const float*)d_in[4];
    const float* W1r = (const float*)d_in[5];
    const float* W2l = (const float*)d_in[6];
    const float* b2  = (const float*)d_in[7];
    const float* W2r = (const float*)d_in[8];
    float* out = (float*)d_out;

    const int N  = in_sizes[0] / DIN;
    const int E1 = in_sizes[1] / 2;
    const int E2 = in_sizes[2] / 2;
    const int NB = (N + SCAN_B - 1) / SCAN_B;

    // Workspace layout
    unsigned short* x_bf = (unsigned short*)d_ws;              // N*512
    unsigned short* h_bf = x_bf + (size_t)N * 512;             // N*512
    unsigned short* c1   = h_bf + (size_t)N * 512;             // N*1024 (c2 aliases)
    unsigned short* c2   = c1;                                  // N*512
    unsigned short* w1_bf = c1 + (size_t)N * 1024;             // [W1l;W1r] 1024x512
    unsigned short* w2_bf = w1_bf + 1024 * 512;                // [W2l;W2r] 512x512
    int* rowptr = (int*)(w2_bf + 512 * 512);                   // N+1
    int* cursor = rowptr + (N + 1);
    int* deg    = cursor + N;
    int* part   = deg + N;                                     // <=256
    int* colbuf = part + 256;                                  // Emax
    (void)ws_size; (void)n_in; (void)out_size;

    // dtype conversions (weights land concatenated: [Wl;Wr])
    {
        int n8 = N * 512 / 8;
        k_f2bf<<<(n8 + 255) / 256, 256, 0, stream>>>(x, x_bf, n8);
        int w8 = 512 * 512 / 8;
        k_f2bf<<<(w8 + 255) / 256, 256, 0, stream>>>(W1l, w1_bf, w8);
        k_f2bf<<<(w8 + 255) / 256, 256, 0, stream>>>(W1r, w1_bf + 512 * 512, w8);
        int v8 = 256 * 512 / 8;
        k_f2bf<<<(v8 + 255) / 256, 256, 0, stream>>>(W2l, w2_bf, v8);
        k_f2bf<<<(v8 + 255) / 256, 256, 0, stream>>>(W2r, w2_bf + 256 * 512, v8);
    }

    auto build_csr = [&](const int* ei, int E) {
        const int* srcp = ei;
        const int* dstp = ei + E;
        hipMemsetAsync(deg, 0, (size_t)N * sizeof(int), stream);
        k_count<<<(E + 255) / 256, 256, 0, stream>>>(dstp, deg, E);
        k_scan_partial<<<NB, SCAN_B, 0, stream>>>(deg, part, N);
        k_scan_part2<<<1, SCAN_B, 0, stream>>>(part, NB, rowptr, N);
        k_scan_final<<<NB, SCAN_B, 0, stream>>>(deg, part, rowptr, cursor, N);
        k_fill<<<(E + 255) / 256, 256, 0, stream>>>(srcp, dstp, cursor, colbuf, E);
    };

    const int MB = (N + TM - 1) / TM;            // 391 row tiles
    const int G8 = (MB + 7) / 8;                 // 49 groups of 8

    // Layer 1: C1 = x @ [W1l;W1r]^T  (N x 1024), then fused mean+bias+relu -> h
    build_csr(ei1, E1);
    k_gemm_mfma<8><<<G8 * 8 * 8, 256, 0, stream>>>(x_bf, w1_bf, c1, N, DIN, 1024);
    k_agg_relu<<<(N + 3) / 4, 256, 0, stream>>>(c1, rowptr, colbuf, b1, h_bf, N);

    // Layer 2: C2 = h @ [W2l;W2r]^T  (N x 512), then fused mean+bias+log_softmax
    build_csr(ei2, E2);
    k_gemm_mfma<4><<<G8 * 8 * 4, 256, 0, stream>>>(h_bf, w2_bf, c2, N, DHID, 512);
    k_agg_lsm<<<(N + 3) / 4, 256, 0, stream>>>(c2, rowptr, colbuf, b2, out, N);
}

// Round 7
// 504.558 us; speedup vs baseline: 4.5037x; 1.0836x over previous
//
#include <hip/hip_runtime.h>
#include <math.h>

#define DIN  512
#define DHID 512
#define DOUT 256

typedef __attribute__((ext_vector_type(8))) short short8;
typedef __attribute__((ext_vector_type(4))) float f32x4;
typedef __attribute__((ext_vector_type(2))) float floatx2;

__device__ __forceinline__ unsigned short f2bf(float f) {
    unsigned int u = __float_as_uint(f);
    u += 0x7fffu + ((u >> 16) & 1u);
    return (unsigned short)(u >> 16);
}
__device__ __forceinline__ float bflo(unsigned int w) { return __uint_as_float(w << 16); }
__device__ __forceinline__ float bfhi(unsigned int w) { return __uint_as_float(w & 0xffff0000u); }

// ---------------------------------------------------------------------------
// fp32 -> bf16, 8 elems per index i
__device__ __forceinline__ void cvt8(const float* __restrict__ in,
                                     unsigned short* __restrict__ out, int i) {
    const float4* iv = (const float4*)in;
    float4 a = iv[2 * i], b = iv[2 * i + 1];
    uint4 o;
    o.x = (unsigned)f2bf(a.x) | ((unsigned)f2bf(a.y) << 16);
    o.y = (unsigned)f2bf(a.z) | ((unsigned)f2bf(a.w) << 16);
    o.z = (unsigned)f2bf(b.x) | ((unsigned)f2bf(b.y) << 16);
    o.w = (unsigned)f2bf(b.z) | ((unsigned)f2bf(b.w) << 16);
    ((uint4*)out)[i] = o;
}

__global__ void k_f2bf(const float* __restrict__ in, unsigned short* __restrict__ out, int n8) {
    int i = blockIdx.x * blockDim.x + threadIdx.x;
    if (i < n8) cvt8(in, out, i);
}

// All four weight matrices in one dispatch. w1=[W1l;W1r] (1024x512),
// w2=[W2l;W2r] (512x512). Group counts: 32768,32768,16384,16384.
__global__ void k_wcvt(const float* __restrict__ W1l, const float* __restrict__ W1r,
                       const float* __restrict__ W2l, const float* __restrict__ W2r,
                       unsigned short* __restrict__ w1, unsigned short* __restrict__ w2) {
    int i = blockIdx.x * blockDim.x + threadIdx.x;
    if (i < 32768)        cvt8(W1l, w1, i);
    else if (i < 65536)   cvt8(W1r, w1 + 262144, i - 32768);
    else if (i < 81920)   cvt8(W2l, w2, i - 65536);
    else if (i < 98304)   cvt8(W2r, w2 + 131072, i - 81920);
}

// ---------------------------------------------------------------------------
// CSR build, both layers batched (blockIdx.y = layer)
__global__ void k_count2(const int* __restrict__ d1, const int* __restrict__ d2,
                         int* __restrict__ deg1, int* __restrict__ deg2, int E1, int E2) {
    int e = blockIdx.x * blockDim.x + threadIdx.x;
    if (blockIdx.y == 0) { if (e < E1) atomicAdd(&deg1[d1[e]], 1); }
    else                 { if (e < E2) atomicAdd(&deg2[d2[e]], 1); }
}

#define SCAN_B 256
__global__ void k_scan_partial2(const int* __restrict__ deg1, const int* __restrict__ deg2,
                                int* __restrict__ part1, int* __restrict__ part2, int n) {
    __shared__ int s[SCAN_B];
    const int* deg = blockIdx.y ? deg2 : deg1;
    int* part      = blockIdx.y ? part2 : part1;
    int i = blockIdx.x * SCAN_B + threadIdx.x;
    s[threadIdx.x] = (i < n) ? deg[i] : 0;
    __syncthreads();
    for (int off = SCAN_B / 2; off > 0; off >>= 1) {
        if (threadIdx.x < off) s[threadIdx.x] += s[threadIdx.x + off];
        __syncthreads();
    }
    if (threadIdx.x == 0) part[blockIdx.x] = s[0];
}

__global__ void k_scan_part2b(int* __restrict__ part1, int* __restrict__ part2, int nb,
                              int* __restrict__ rowptr1, int* __restrict__ rowptr2, int n) {
    __shared__ int s[SCAN_B];
    int* part   = blockIdx.x ? part2 : part1;
    int* rowptr = blockIdx.x ? rowptr2 : rowptr1;
    int v = (threadIdx.x < nb) ? part[threadIdx.x] : 0;
    s[threadIdx.x] = v;
    __syncthreads();
    for (int off = 1; off < SCAN_B; off <<= 1) {
        int t = (threadIdx.x >= off) ? s[threadIdx.x - off] : 0;
        __syncthreads();
        s[threadIdx.x] += t;
        __syncthreads();
    }
    if (threadIdx.x < nb) part[threadIdx.x] = s[threadIdx.x] - v;  // exclusive
    if (threadIdx.x == SCAN_B - 1) rowptr[n] = s[SCAN_B - 1];
}

__global__ void k_scan_final2(const int* __restrict__ deg1, const int* __restrict__ deg2,
                              const int* __restrict__ part1, const int* __restrict__ part2,
                              int* __restrict__ rowptr1, int* __restrict__ rowptr2,
                              int* __restrict__ cursor1, int* __restrict__ cursor2, int n) {
    __shared__ int s[SCAN_B];
    const int* deg  = blockIdx.y ? deg2 : deg1;
    const int* part = blockIdx.y ? part2 : part1;
    int* rowptr     = blockIdx.y ? rowptr2 : rowptr1;
    int* cursor     = blockIdx.y ? cursor2 : cursor1;
    int i = blockIdx.x * SCAN_B + threadIdx.x;
    int v = (i < n) ? deg[i] : 0;
    s[threadIdx.x] = v;
    __syncthreads();
    for (int off = 1; off < SCAN_B; off <<= 1) {
        int t = (threadIdx.x >= off) ? s[threadIdx.x - off] : 0;
        __syncthreads();
        s[threadIdx.x] += t;
        __syncthreads();
    }
    if (i < n) {
        int ex = part[blockIdx.y ? blockIdx.x : blockIdx.x] + s[threadIdx.x] - v;
        rowptr[i] = ex;
        cursor[i] = ex;
    }
}

__global__ void k_fill2(const int* __restrict__ s1, const int* __restrict__ d1,
                        const int* __restrict__ s2, const int* __restrict__ d2,
                        int* __restrict__ cur1, int* __restrict__ cur2,
                        int* __restrict__ col1, int* __restrict__ col2, int E1, int E2) {
    int e = blockIdx.x * blockDim.x + threadIdx.x;
    if (blockIdx.y == 0) {
        if (e < E1) { int p = atomicAdd(&cur1[d1[e]], 1); col1[p] = s1[e]; }
    } else {
        if (e < E2) { int p = atomicAdd(&cur2[d2[e]], 1); col2[p] = s2[e]; }
    }
}

// ---------------------------------------------------------------------------
// bf16 MFMA GEMM: out = A @ W^T. SPLIT=1 (layer 1): columns [0,NC/2) -> fp8
// e4m3 buffer C8 (gathered by agg — 2x less fabric traffic), columns
// [NC/2,NC) -> bf16 C16. SPLIT=0: all columns bf16 into C16 (stride NC).
// XCD-aware 1D swizzle (round-4 verified: FETCH 203->58 MB).
#define TM 128
#define TN 128
#define TK 32

template <int NCT, int SPLIT>
__global__ __launch_bounds__(256, 3)
void k_gemm_mfma(const unsigned short* __restrict__ A, const unsigned short* __restrict__ W,
                 unsigned char* __restrict__ C8, unsigned short* __restrict__ C16,
                 int M, int K, int NC) {
    __shared__ __align__(16) unsigned short As[TM * TK];
    __shared__ __align__(16) unsigned short Bs[TN * TK];
    const int id = blockIdx.x;
    const int xcd = id & 7;
    const int s = id >> 3;
    const int row0 = ((s / NCT) * 8 + xcd) * TM;
    const int col0 = (s % NCT) * TN;
    if (row0 >= M) return;

    const int t = threadIdx.x;
    const int lane = t & 63;
    const int w = t >> 6;
    const int wr = (w >> 1) * 64;
    const int wc = (w & 1) * 64;
    const int lm = lane & 15;
    const int k8 = (lane >> 4) * 8;

    f32x4 acc[4][4];
#pragma unroll
    for (int i = 0; i < 4; ++i)
#pragma unroll
        for (int j = 0; j < 4; ++j) acc[i][j] = (f32x4){0.f, 0.f, 0.f, 0.f};

    const int ar = t >> 2;
    const int as = (t & 3) * 8;

    for (int k0 = 0; k0 < K; k0 += TK) {
        int r1 = row0 + ar;      if (r1 >= M) r1 = M - 1;
        int r2 = row0 + ar + 64; if (r2 >= M) r2 = M - 1;
        const unsigned short* ga1 = A + (size_t)r1 * K + k0 + as;
        const unsigned short* ga2 = A + (size_t)r2 * K + k0 + as;
        const unsigned short* gb1 = W + (size_t)(col0 + ar) * K + k0 + as;
        const unsigned short* gb2 = W + (size_t)(col0 + ar + 64) * K + k0 + as;
        __builtin_amdgcn_global_load_lds(
            (const __attribute__((address_space(1))) unsigned int*)ga1,
            (__attribute__((address_space(3))) unsigned int*)&As[t * 8], 16, 0, 0);
        __builtin_amdgcn_global_load_lds(
            (const __attribute__((address_space(1))) unsigned int*)ga2,
            (__attribute__((address_space(3))) unsigned int*)&As[(t + 256) * 8], 16, 0, 0);
        __builtin_amdgcn_global_load_lds(
            (const __attribute__((address_space(1))) unsigned int*)gb1,
            (__attribute__((address_space(3))) unsigned int*)&Bs[t * 8], 16, 0, 0);
        __builtin_amdgcn_global_load_lds(
            (const __attribute__((address_space(1))) unsigned int*)gb2,
            (__attribute__((address_space(3))) unsigned int*)&Bs[(t + 256) * 8], 16, 0, 0);
        __syncthreads();

        short8 a[4], b[4];
#pragma unroll
        for (int i = 0; i < 4; ++i)
            a[i] = *(const short8*)&As[(wr + i * 16 + lm) * TK + k8];
#pragma unroll
        for (int j = 0; j < 4; ++j)
            b[j] = *(const short8*)&Bs[(wc + j * 16 + lm) * TK + k8];
#pragma unroll
        for (int i = 0; i < 4; ++i)
#pragma unroll
            for (int j = 0; j < 4; ++j)
                acc[i][j] = __builtin_amdgcn_mfma_f32_16x16x32_bf16(a[i], b[j], acc[i][j], 0, 0, 0);
        __syncthreads();
    }

    // epilogue: D row = quad*4 + reg, col = lane&15. col0 is 128-aligned so
    // the fp8/bf16 split (at NC/2, NC=1024) is block-uniform.
    const int qr = (lane >> 4) * 4;
    const bool lo_half = SPLIT && (col0 < NC / 2);
    const int cadj = SPLIT ? NC / 2 : 0;
#pragma unroll
    for (int i = 0; i < 4; ++i) {
#pragma unroll
        for (int r = 0; r < 4; ++r) {
            int gr = row0 + wr + i * 16 + qr + r;
            if (gr >= M) continue;
#pragma unroll
            for (int j = 0; j < 4; ++j) {
                int gc = col0 + wc + j * 16 + lm;
                float v = acc[i][j][r];
                if (SPLIT && lo_half) {
                    int p = __builtin_amdgcn_cvt_pk_fp8_f32(v, v, 0, 0);
                    C8[(size_t)gr * (NC / 2) + gc] = (unsigned char)p;
                } else {
                    C16[(size_t)gr * (NC - cadj) + (gc - cadj)] = f2bf(v);
                }
            }
        }
    }
}

// ---------------------------------------------------------------------------
// Layer-1 fused epilogue: h[i] = relu( mean_j C8[j] + C16r[i] + b1 ), bf16 out.
// C8: y_l rows, 512 fp8 = 64 uint2. C16r: y_r rows, 512 bf16 = 64 uint4.
// One wave per node, lane covers dims 8*lane..8*lane+7. Edge loop x4 unrolled.
__global__ void k_agg_relu(const unsigned char* __restrict__ C8,
                           const unsigned short* __restrict__ C16r,
                           const int* __restrict__ rowptr, const int* __restrict__ col,
                           const float* __restrict__ b1, unsigned short* __restrict__ H, int n) {
    int node = blockIdx.x * (blockDim.x >> 6) + (threadIdx.x >> 6);
    int lane = threadIdx.x & 63;
    if (node >= n) return;
    int beg = rowptr[node], end = rowptr[node + 1];
    float acc[8] = {};
    const uint2* Cv = (const uint2*)C8;   // row stride 64 uint2
    int e = beg;
    for (; e + 4 <= end; e += 4) {
        int c0 = col[e], c1 = col[e + 1], c2 = col[e + 2], c3 = col[e + 3];
        uint2 v0 = Cv[(size_t)c0 * 64 + lane];
        uint2 v1 = Cv[(size_t)c1 * 64 + lane];
        uint2 v2 = Cv[(size_t)c2 * 64 + lane];
        uint2 v3 = Cv[(size_t)c3 * 64 + lane];
        unsigned int ws[8] = {v0.x, v0.y, v1.x, v1.y, v2.x, v2.y, v3.x, v3.y};
#pragma unroll
        for (int q = 0; q < 8; ++q) {
            floatx2 flo = __builtin_amdgcn_cvt_pk_f32_fp8(ws[q], 0);
            floatx2 fhi = __builtin_amdgcn_cvt_pk_f32_fp8(ws[q], 1);
            int base = (q & 1) * 4;
            acc[base + 0] += flo.x; acc[base + 1] += flo.y;
            acc[base + 2] += fhi.x; acc[base + 3] += fhi.y;
        }
    }
    for (; e < end; ++e) {
        uint2 v = Cv[(size_t)col[e] * 64 + lane];
        floatx2 f0 = __builtin_amdgcn_cvt_pk_f32_fp8(v.x, 0);
        floatx2 f1 = __builtin_amdgcn_cvt_pk_f32_fp8(v.x, 1);
        floatx2 f2 = __builtin_amdgcn_cvt_pk_f32_fp8(v.y, 0);
        floatx2 f3 = __builtin_amdgcn_cvt_pk_f32_fp8(v.y, 1);
        acc[0] += f0.x; acc[1] += f0.y; acc[2] += f1.x; acc[3] += f1.y;
        acc[4] += f2.x; acc[5] += f2.y; acc[6] += f3.x; acc[7] += f3.y;
    }
    float inv = 1.0f / fmaxf((float)(end - beg), 1.0f);
    uint4 yr = ((const uint4*)C16r)[(size_t)node * 64 + lane];
    unsigned int wr[4] = {yr.x, yr.y, yr.z, yr.w};
    float4 bv0 = ((const float4*)b1)[2 * lane];
    float4 bv1 = ((const float4*)b1)[2 * lane + 1];
    float bb[8] = {bv0.x, bv0.y, bv0.z, bv0.w, bv1.x, bv1.y, bv1.z, bv1.w};
    unsigned int r[4];
#pragma unroll
    for (int q = 0; q < 4; ++q) {
        float v0 = fmaxf(acc[2 * q] * inv     + bflo(wr[q]) + bb[2 * q],     0.f);
        float v1 = fmaxf(acc[2 * q + 1] * inv + bfhi(wr[q]) + bb[2 * q + 1], 0.f);
        r[q] = (unsigned)f2bf(v0) | ((unsigned)f2bf(v1) << 16);
    }
    uint4 o; o.x = r[0]; o.y = r[1]; o.z = r[2]; o.w = r[3];
    ((uint4*)H)[(size_t)node * 64 + lane] = o;
}

// ---------------------------------------------------------------------------
// Layer-2 fused epilogue: out[i] = log_softmax( mean_j C2l[j] + C2r[i] + b2 ).
// C2 rows: [y_l(256 bf16) | y_r(256 bf16)] = 128 uint2 (all bf16 — fp8 here
// would hit final logits directly). Edge loop x4 unrolled. Output fp32.
__global__ void k_agg_lsm(const unsigned short* __restrict__ C2,
                          const int* __restrict__ rowptr, const int* __restrict__ col,
                          const float* __restrict__ b2, float* __restrict__ O, int n) {
    int node = blockIdx.x * (blockDim.x >> 6) + (threadIdx.x >> 6);
    int lane = threadIdx.x & 63;
    if (node >= n) return;
    int beg = rowptr[node], end = rowptr[node + 1];
    float acc[4] = {};
    const uint2* Cv = (const uint2*)C2;   // row stride 128 uint2
    int e = beg;
    for (; e + 4 <= end; e += 4) {
        int c0 = col[e], c1 = col[e + 1], c2 = col[e + 2], c3 = col[e + 3];
        uint2 v0 = Cv[(size_t)c0 * 128 + lane];
        uint2 v1 = Cv[(size_t)c1 * 128 + lane];
        uint2 v2 = Cv[(size_t)c2 * 128 + lane];
        uint2 v3 = Cv[(size_t)c3 * 128 + lane];
        acc[0] += bflo(v0.x) + bflo(v1.x) + bflo(v2.x) + bflo(v3.x);
        acc[1] += bfhi(v0.x) + bfhi(v1.x) + bfhi(v2.x) + bfhi(v3.x);
        acc[2] += bflo(v0.y) + bflo(v1.y) + bflo(v2.y) + bflo(v3.y);
        acc[3] += bfhi(v0.y) + bfhi(v1.y) + bfhi(v2.y) + bfhi(v3.y);
    }
    for (; e < end; ++e) {
        uint2 v = Cv[(size_t)col[e] * 128 + lane];
        acc[0] += bflo(v.x); acc[1] += bfhi(v.x);
        acc[2] += bflo(v.y); acc[3] += bfhi(v.y);
    }
    float inv = 1.0f / fmaxf((float)(end - beg), 1.0f);
    uint2 yr = Cv[(size_t)node * 128 + 64 + lane];
    float4 bv = ((const float4*)b2)[lane];
    float val[4];
    val[0] = acc[0] * inv + bflo(yr.x) + bv.x;
    val[1] = acc[1] * inv + bfhi(yr.x) + bv.y;
    val[2] = acc[2] * inv + bflo(yr.y) + bv.z;
    val[3] = acc[3] * inv + bfhi(yr.y) + bv.w;
    float mx = fmaxf(fmaxf(val[0], val[1]), fmaxf(val[2], val[3]));
#pragma unroll
    for (int off = 32; off > 0; off >>= 1) mx = fmaxf(mx, __shfl_xor(mx, off));
    float s = expf(val[0] - mx) + expf(val[1] - mx) + expf(val[2] - mx) + expf(val[3] - mx);
#pragma unroll
    for (int off = 32; off > 0; off >>= 1) s += __shfl_xor(s, off);
    float lse = mx + logf(s);
    float4 o = make_float4(val[0] - lse, val[1] - lse, val[2] - lse, val[3] - lse);
    ((float4*)O)[(size_t)node * 64 + lane] = o;
}

// ---------------------------------------------------------------------------
extern "C" void kernel_launch(void* const* d_in, const int* in_sizes, int n_in,
                              void* d_out, int out_size, void* d_ws, size_t ws_size,
                              hipStream_t stream) {
    const float* x   = (const float*)d_in[0];
    const int*   ei1 = (const int*)d_in[1];
    const int*   ei2 = (const int*)d_in[2];
    const float* W1l = (const float*)d_in[3];
    const float* b1  = (const float*)d_in[4];
    const float* W1r = (const float*)d_in[5];
    const float* W2l = (const float*)d_in[6];
    const float* b2  = (const float*)d_in[7];
    const float* W2r = (const float*)d_in[8];
    float* out = (float*)d_out;

    const int N  = in_sizes[0] / DIN;
    const int E1 = in_sizes[1] / 2;
    const int E2 = in_sizes[2] / 2;
    const int Emax = (E1 > E2) ? E1 : E2;
    const int NB = (N + SCAN_B - 1) / SCAN_B;

    // Workspace layout
    unsigned short* x_bf  = (unsigned short*)d_ws;             // N*512 bf16
    unsigned short* h_bf  = x_bf + (size_t)N * 512;            // N*512 bf16
    unsigned char*  c1l   = (unsigned char*)(h_bf + (size_t)N * 512);  // N*512 fp8
    unsigned short* c1r   = (unsigned short*)(c1l + (size_t)N * 512);  // N*512 bf16
    unsigned short* c2    = (unsigned short*)c1l;              // N*512 bf16 (aliases c1l/c1r — c1 dead before GEMM2)
    unsigned short* w1_bf = c1r + (size_t)N * 512;             // 1024*512
    unsigned short* w2_bf = w1_bf + 1024 * 512;                // 512*512
    int* rowptr1 = (int*)(w2_bf + 512 * 512);                  // N+1
    int* rowptr2 = rowptr1 + (N + 1);                          // N+1
    int* cursor1 = rowptr2 + (N + 1);                          // N
    int* cursor2 = cursor1 + N;                                // N
    int* deg1    = cursor2 + N;                                // N
    int* deg2    = deg1 + N;                                   // N (contiguous w/ deg1)
    int* part1   = deg2 + N;                                   // 256
    int* part2   = part1 + 256;                                // 256
    int* col1    = part2 + 256;                                // E1
    int* col2    = col1 + E1;                                  // E2
    (void)ws_size; (void)n_in; (void)out_size;

    // conversions
    {
        int n8 = N * 512 / 8;
        k_f2bf<<<(n8 + 255) / 256, 256, 0, stream>>>(x, x_bf, n8);
        k_wcvt<<<(98304 + 255) / 256, 256, 0, stream>>>(W1l, W1r, W2l, W2r, w1_bf, w2_bf);
    }

    // both CSRs, batched
    hipMemsetAsync(deg1, 0, (size_t)2 * N * sizeof(int), stream);
    {
        dim3 ge((Emax + 255) / 256, 2);
        k_count2<<<ge, 256, 0, stream>>>(ei1 + E1, ei2 + E2, deg1, deg2, E1, E2);
        k_scan_partial2<<<dim3(NB, 2), SCAN_B, 0, stream>>>(deg1, deg2, part1, part2, N);
        k_scan_part2b<<<2, SCAN_B, 0, stream>>>(part1, part2, NB, rowptr1, rowptr2, N);
        k_scan_final2<<<dim3(NB, 2), SCAN_B, 0, stream>>>(deg1, deg2, part1, part2,
                                                          rowptr1, rowptr2, cursor1, cursor2, N);
        k_fill2<<<ge, 256, 0, stream>>>(ei1, ei1 + E1, ei2, ei2 + E2,
                                        cursor1, cursor2, col1, col2, E1, E2);
    }

    const int MB = (N + TM - 1) / TM;            // 391 row tiles
    const int G8 = (MB + 7) / 8;                 // 49 groups of 8

    // Layer 1: [y_l|y_r] = x @ [W1l;W1r]^T; y_l -> fp8, y_r -> bf16.
    k_gemm_mfma<8, 1><<<G8 * 8 * 8, 256, 0, stream>>>(x_bf, w1_bf, c1l, c1r, N, DIN, 1024);
    k_agg_relu<<<(N + 3) / 4, 256, 0, stream>>>(c1l, c1r, rowptr1, col1, b1, h_bf, N);

    // Layer 2: C2 = h @ [W2l;W2r]^T (bf16), then fused mean+bias+log_softmax.
    k_gemm_mfma<4, 0><<<G8 * 8 * 4, 256, 0, stream>>>(h_bf, w2_bf, (unsigned char*)nullptr, c2, N, DHID, 512);
    k_agg_lsm<<<(N + 3) / 4, 256, 0, stream>>>(c2, rowptr2, col2, b2, out, N);
}

// Round 8
// 500.401 us; speedup vs baseline: 4.5411x; 1.0083x over previous
//
#include <hip/hip_runtime.h>
#include <math.h>

#define DIN  512
#define DHID 512
#define DOUT 256

typedef __attribute__((ext_vector_type(8))) short short8;
typedef __attribute__((ext_vector_type(4))) float f32x4;
typedef __attribute__((ext_vector_type(2))) float floatx2;

__device__ __forceinline__ unsigned short f2bf(float f) {
    unsigned int u = __float_as_uint(f);
    u += 0x7fffu + ((u >> 16) & 1u);
    return (unsigned short)(u >> 16);
}
__device__ __forceinline__ float bflo(unsigned int w) { return __uint_as_float(w << 16); }
__device__ __forceinline__ float bfhi(unsigned int w) { return __uint_as_float(w & 0xffff0000u); }

// ---------------------------------------------------------------------------
// fp32 -> bf16, 8 elems per index i
__device__ __forceinline__ void cvt8(const float* __restrict__ in,
                                     unsigned short* __restrict__ out, int i) {
    const float4* iv = (const float4*)in;
    float4 a = iv[2 * i], b = iv[2 * i + 1];
    uint4 o;
    o.x = (unsigned)f2bf(a.x) | ((unsigned)f2bf(a.y) << 16);
    o.y = (unsigned)f2bf(a.z) | ((unsigned)f2bf(a.w) << 16);
    o.z = (unsigned)f2bf(b.x) | ((unsigned)f2bf(b.y) << 16);
    o.w = (unsigned)f2bf(b.z) | ((unsigned)f2bf(b.w) << 16);
    ((uint4*)out)[i] = o;
}

__global__ void k_f2bf(const float* __restrict__ in, unsigned short* __restrict__ out, int n8) {
    int i = blockIdx.x * blockDim.x + threadIdx.x;
    if (i < n8) cvt8(in, out, i);
}

__global__ void k_wcvt(const float* __restrict__ W1l, const float* __restrict__ W1r,
                       const float* __restrict__ W2l, const float* __restrict__ W2r,
                       unsigned short* __restrict__ w1, unsigned short* __restrict__ w2) {
    int i = blockIdx.x * blockDim.x + threadIdx.x;
    if (i < 32768)        cvt8(W1l, w1, i);
    else if (i < 65536)   cvt8(W1r, w1 + 262144, i - 32768);
    else if (i < 81920)   cvt8(W2l, w2, i - 65536);
    else if (i < 98304)   cvt8(W2r, w2 + 131072, i - 81920);
}

// ---------------------------------------------------------------------------
// CSR build, both layers batched (blockIdx.y = layer)
__global__ void k_count2(const int* __restrict__ d1, const int* __restrict__ d2,
                         int* __restrict__ deg1, int* __restrict__ deg2, int E1, int E2) {
    int e = blockIdx.x * blockDim.x + threadIdx.x;
    if (blockIdx.y == 0) { if (e < E1) atomicAdd(&deg1[d1[e]], 1); }
    else                 { if (e < E2) atomicAdd(&deg2[d2[e]], 1); }
}

#define SCAN_B 256
__global__ void k_scan_partial2(const int* __restrict__ deg1, const int* __restrict__ deg2,
                                int* __restrict__ part1, int* __restrict__ part2, int n) {
    __shared__ int s[SCAN_B];
    const int* deg = blockIdx.y ? deg2 : deg1;
    int* part      = blockIdx.y ? part2 : part1;
    int i = blockIdx.x * SCAN_B + threadIdx.x;
    s[threadIdx.x] = (i < n) ? deg[i] : 0;
    __syncthreads();
    for (int off = SCAN_B / 2; off > 0; off >>= 1) {
        if (threadIdx.x < off) s[threadIdx.x] += s[threadIdx.x + off];
        __syncthreads();
    }
    if (threadIdx.x == 0) part[blockIdx.x] = s[0];
}

__global__ void k_scan_part2b(int* __restrict__ part1, int* __restrict__ part2, int nb,
                              int* __restrict__ rowptr1, int* __restrict__ rowptr2, int n) {
    __shared__ int s[SCAN_B];
    int* part   = blockIdx.x ? part2 : part1;
    int* rowptr = blockIdx.x ? rowptr2 : rowptr1;
    int v = (threadIdx.x < nb) ? part[threadIdx.x] : 0;
    s[threadIdx.x] = v;
    __syncthreads();
    for (int off = 1; off < SCAN_B; off <<= 1) {
        int t = (threadIdx.x >= off) ? s[threadIdx.x - off] : 0;
        __syncthreads();
        s[threadIdx.x] += t;
        __syncthreads();
    }
    if (threadIdx.x < nb) part[threadIdx.x] = s[threadIdx.x] - v;  // exclusive
    if (threadIdx.x == SCAN_B - 1) rowptr[n] = s[SCAN_B - 1];
}

__global__ void k_scan_final2(const int* __restrict__ deg1, const int* __restrict__ deg2,
                              const int* __restrict__ part1, const int* __restrict__ part2,
                              int* __restrict__ rowptr1, int* __restrict__ rowptr2,
                              int* __restrict__ cursor1, int* __restrict__ cursor2, int n) {
    __shared__ int s[SCAN_B];
    const int* deg  = blockIdx.y ? deg2 : deg1;
    const int* part = blockIdx.y ? part2 : part1;
    int* rowptr     = blockIdx.y ? rowptr2 : rowptr1;
    int* cursor     = blockIdx.y ? cursor2 : cursor1;
    int i = blockIdx.x * SCAN_B + threadIdx.x;
    int v = (i < n) ? deg[i] : 0;
    s[threadIdx.x] = v;
    __syncthreads();
    for (int off = 1; off < SCAN_B; off <<= 1) {
        int t = (threadIdx.x >= off) ? s[threadIdx.x - off] : 0;
        __syncthreads();
        s[threadIdx.x] += t;
        __syncthreads();
    }
    if (i < n) {
        int ex = part[blockIdx.x] + s[threadIdx.x] - v;
        rowptr[i] = ex;
        cursor[i] = ex;
    }
}

__global__ void k_fill2(const int* __restrict__ s1, const int* __restrict__ d1,
                        const int* __restrict__ s2, const int* __restrict__ d2,
                        int* __restrict__ cur1, int* __restrict__ cur2,
                        int* __restrict__ col1, int* __restrict__ col2, int E1, int E2) {
    int e = blockIdx.x * blockDim.x + threadIdx.x;
    if (blockIdx.y == 0) {
        if (e < E1) { int p = atomicAdd(&cur1[d1[e]], 1); col1[p] = s1[e]; }
    } else {
        if (e < E2) { int p = atomicAdd(&cur2[d2[e]], 1); col2[p] = s2[e]; }
    }
}

// ---------------------------------------------------------------------------
// bf16 MFMA GEMM: out = A @ W^T. SPLIT=1: columns [0,NC/2) -> fp8 e4m3 C8,
// columns [NC/2,NC) -> bf16 C16 (stride NC/2 each). SPLIT=0: all bf16.
// LDS layout is XOR-swizzled: row R's k-chunk q (16B) lives at slot
// q ^ ((R>>1)&3) — spreads fragment reads over all 8 bank groups (2
// lanes/bank = free). Staging stays lane-contiguous in LDS (global_load_lds
// requirement); only WHICH global chunk a thread fetches changes.
#define TM 128
#define TN 128
#define TK 32

template <int NCT, int SPLIT>
__global__ __launch_bounds__(256, 4)
void k_gemm_mfma(const unsigned short* __restrict__ A, const unsigned short* __restrict__ W,
                 unsigned char* __restrict__ C8, unsigned short* __restrict__ C16,
                 int M, int K, int NC) {
    __shared__ __align__(16) unsigned short As[TM * TK];
    __shared__ __align__(16) unsigned short Bs[TN * TK];
    const int id = blockIdx.x;
    const int xcd = id & 7;
    const int s = id >> 3;
    const int row0 = ((s / NCT) * 8 + xcd) * TM;
    const int col0 = (s % NCT) * TN;
    if (row0 >= M) return;

    const int t = threadIdx.x;
    const int lane = t & 63;
    const int w = t >> 6;
    const int wr = (w >> 1) * 64;
    const int wc = (w & 1) * 64;
    const int lm = lane & 15;
    const int q = lane >> 4;             // logical k-chunk 0..3 (8 bf16 each)

    f32x4 acc[4][4];
#pragma unroll
    for (int i = 0; i < 4; ++i)
#pragma unroll
        for (int j = 0; j < 4; ++j) acc[i][j] = (f32x4){0.f, 0.f, 0.f, 0.f};

    // staging: LDS slot t holds row ar=t>>2, slot-chunk c=t&3; that slot must
    // receive global chunk s = c ^ ((row>>1)&3) = (t&3) ^ ((t>>3)&3).
    // Rows ar+64 (slot t+256) have the same XOR term (64 rows = +32 pairs).
    const int ar = t >> 2;
    const int as = (((t & 3) ^ ((t >> 3) & 3))) * 8;

    for (int k0 = 0; k0 < K; k0 += TK) {
        int r1 = row0 + ar;      if (r1 >= M) r1 = M - 1;
        int r2 = row0 + ar + 64; if (r2 >= M) r2 = M - 1;
        const unsigned short* ga1 = A + (size_t)r1 * K + k0 + as;
        const unsigned short* ga2 = A + (size_t)r2 * K + k0 + as;
        const unsigned short* gb1 = W + (size_t)(col0 + ar) * K + k0 + as;
        const unsigned short* gb2 = W + (size_t)(col0 + ar + 64) * K + k0 + as;
        __builtin_amdgcn_global_load_lds(
            (const __attribute__((address_space(1))) unsigned int*)ga1,
            (__attribute__((address_space(3))) unsigned int*)&As[t * 8], 16, 0, 0);
        __builtin_amdgcn_global_load_lds(
            (const __attribute__((address_space(1))) unsigned int*)ga2,
            (__attribute__((address_space(3))) unsigned int*)&As[(t + 256) * 8], 16, 0, 0);
        __builtin_amdgcn_global_load_lds(
            (const __attribute__((address_space(1))) unsigned int*)gb1,
            (__attribute__((address_space(3))) unsigned int*)&Bs[t * 8], 16, 0, 0);
        __builtin_amdgcn_global_load_lds(
            (const __attribute__((address_space(1))) unsigned int*)gb2,
            (__attribute__((address_space(3))) unsigned int*)&Bs[(t + 256) * 8], 16, 0, 0);
        __syncthreads();

        short8 a[4], b[4];
#pragma unroll
        for (int i = 0; i < 4; ++i) {
            int R = wr + i * 16 + lm;
            a[i] = *(const short8*)&As[R * TK + ((q ^ ((R >> 1) & 3)) * 8)];
        }
#pragma unroll
        for (int j = 0; j < 4; ++j) {
            int R = wc + j * 16 + lm;
            b[j] = *(const short8*)&Bs[R * TK + ((q ^ ((R >> 1) & 3)) * 8)];
        }
#pragma unroll
        for (int i = 0; i < 4; ++i)
#pragma unroll
            for (int j = 0; j < 4; ++j)
                acc[i][j] = __builtin_amdgcn_mfma_f32_16x16x32_bf16(a[i], b[j], acc[i][j], 0, 0, 0);
        __syncthreads();
    }

    // epilogue: D row = quad*4 + reg, col = lane&15. col0 is 128-aligned so
    // the fp8/bf16 split (at NC/2) is block-uniform.
    const int qr = (lane >> 4) * 4;
    const bool lo_half = SPLIT && (col0 < NC / 2);
    const int cadj = SPLIT ? NC / 2 : 0;
#pragma unroll
    for (int i = 0; i < 4; ++i) {
#pragma unroll
        for (int r = 0; r < 4; ++r) {
            int gr = row0 + wr + i * 16 + qr + r;
            if (gr >= M) continue;
#pragma unroll
            for (int j = 0; j < 4; ++j) {
                int gc = col0 + wc + j * 16 + lm;
                float v = acc[i][j][r];
                if (SPLIT && lo_half) {
                    int p = __builtin_amdgcn_cvt_pk_fp8_f32(v, v, 0, 0);
                    C8[(size_t)gr * (NC / 2) + gc] = (unsigned char)p;
                } else {
                    C16[(size_t)gr * (NC - cadj) + (gc - cadj)] = f2bf(v);
                }
            }
        }
    }
}

// ---------------------------------------------------------------------------
// Layer-1 fused epilogue: h[i] = relu( mean_j C8[j] + C16r[i] + b1 ), bf16 out.
// C8: y_l rows, 512 fp8 = 64 uint2. C16r: y_r rows, 512 bf16 = 64 uint4.
__global__ void k_agg_relu(const unsigned char* __restrict__ C8,
                           const unsigned short* __restrict__ C16r,
                           const int* __restrict__ rowptr, const int* __restrict__ col,
                           const float* __restrict__ b1, unsigned short* __restrict__ H, int n) {
    int node = blockIdx.x * (blockDim.x >> 6) + (threadIdx.x >> 6);
    int lane = threadIdx.x & 63;
    if (node >= n) return;
    int beg = rowptr[node], end = rowptr[node + 1];
    float acc[8] = {};
    const uint2* Cv = (const uint2*)C8;   // row stride 64 uint2
    int e = beg;
    for (; e + 4 <= end; e += 4) {
        int c0 = col[e], c1 = col[e + 1], c2 = col[e + 2], c3 = col[e + 3];
        uint2 v0 = Cv[(size_t)c0 * 64 + lane];
        uint2 v1 = Cv[(size_t)c1 * 64 + lane];
        uint2 v2 = Cv[(size_t)c2 * 64 + lane];
        uint2 v3 = Cv[(size_t)c3 * 64 + lane];
        unsigned int ws[8] = {v0.x, v0.y, v1.x, v1.y, v2.x, v2.y, v3.x, v3.y};
#pragma unroll
        for (int qq = 0; qq < 8; ++qq) {
            floatx2 flo = __builtin_amdgcn_cvt_pk_f32_fp8(ws[qq], 0);
            floatx2 fhi = __builtin_amdgcn_cvt_pk_f32_fp8(ws[qq], 1);
            int base = (qq & 1) * 4;
            acc[base + 0] += flo.x; acc[base + 1] += flo.y;
            acc[base + 2] += fhi.x; acc[base + 3] += fhi.y;
        }
    }
    for (; e < end; ++e) {
        uint2 v = Cv[(size_t)col[e] * 64 + lane];
        floatx2 f0 = __builtin_amdgcn_cvt_pk_f32_fp8(v.x, 0);
        floatx2 f1 = __builtin_amdgcn_cvt_pk_f32_fp8(v.x, 1);
        floatx2 f2 = __builtin_amdgcn_cvt_pk_f32_fp8(v.y, 0);
        floatx2 f3 = __builtin_amdgcn_cvt_pk_f32_fp8(v.y, 1);
        acc[0] += f0.x; acc[1] += f0.y; acc[2] += f1.x; acc[3] += f1.y;
        acc[4] += f2.x; acc[5] += f2.y; acc[6] += f3.x; acc[7] += f3.y;
    }
    float inv = 1.0f / fmaxf((float)(end - beg), 1.0f);
    uint4 yr = ((const uint4*)C16r)[(size_t)node * 64 + lane];
    unsigned int wr[4] = {yr.x, yr.y, yr.z, yr.w};
    float4 bv0 = ((const float4*)b1)[2 * lane];
    float4 bv1 = ((const float4*)b1)[2 * lane + 1];
    float bb[8] = {bv0.x, bv0.y, bv0.z, bv0.w, bv1.x, bv1.y, bv1.z, bv1.w};
    unsigned int r[4];
#pragma unroll
    for (int qq = 0; qq < 4; ++qq) {
        float v0 = fmaxf(acc[2 * qq] * inv     + bflo(wr[qq]) + bb[2 * qq],     0.f);
        float v1 = fmaxf(acc[2 * qq + 1] * inv + bfhi(wr[qq]) + bb[2 * qq + 1], 0.f);
        r[qq] = (unsigned)f2bf(v0) | ((unsigned)f2bf(v1) << 16);
    }
    uint4 o; o.x = r[0]; o.y = r[1]; o.z = r[2]; o.w = r[3];
    ((uint4*)H)[(size_t)node * 64 + lane] = o;
}

// ---------------------------------------------------------------------------
// Layer-2 fused epilogue: out[i] = log_softmax( mean_j C8[j] + C16r[i] + b2 ).
// C8: y_l rows, 256 fp8 = 64 uint (lane covers dims 4*lane..4*lane+3).
// C16r: y_r rows, 256 bf16 = 64 uint2. Output fp32.
__global__ void k_agg_lsm(const unsigned char* __restrict__ C8,
                          const unsigned short* __restrict__ C16r,
                          const int* __restrict__ rowptr, const int* __restrict__ col,
                          const float* __restrict__ b2, float* __restrict__ O, int n) {
    int node = blockIdx.x * (blockDim.x >> 6) + (threadIdx.x >> 6);
    int lane = threadIdx.x & 63;
    if (node >= n) return;
    int beg = rowptr[node], end = rowptr[node + 1];
    float acc[4] = {};
    const unsigned int* Cv = (const unsigned int*)C8;   // row stride 64 uint
    int e = beg;
    for (; e + 4 <= end; e += 4) {
        int c0 = col[e], c1 = col[e + 1], c2 = col[e + 2], c3 = col[e + 3];
        unsigned int u0 = Cv[(size_t)c0 * 64 + lane];
        unsigned int u1 = Cv[(size_t)c1 * 64 + lane];
        unsigned int u2 = Cv[(size_t)c2 * 64 + lane];
        unsigned int u3 = Cv[(size_t)c3 * 64 + lane];
        unsigned int us[4] = {u0, u1, u2, u3};
#pragma unroll
        for (int qq = 0; qq < 4; ++qq) {
            floatx2 flo = __builtin_amdgcn_cvt_pk_f32_fp8(us[qq], 0);
            floatx2 fhi = __builtin_amdgcn_cvt_pk_f32_fp8(us[qq], 1);
            acc[0] += flo.x; acc[1] += flo.y; acc[2] += fhi.x; acc[3] += fhi.y;
        }
    }
    for (; e < end; ++e) {
        unsigned int u = Cv[(size_t)col[e] * 64 + lane];
        floatx2 flo = __builtin_amdgcn_cvt_pk_f32_fp8(u, 0);
        floatx2 fhi = __builtin_amdgcn_cvt_pk_f32_fp8(u, 1);
        acc[0] += flo.x; acc[1] += flo.y; acc[2] += fhi.x; acc[3] += fhi.y;
    }
    float inv = 1.0f / fmaxf((float)(end - beg), 1.0f);
    uint2 yr = ((const uint2*)C16r)[(size_t)node * 64 + lane];
    float4 bv = ((const float4*)b2)[lane];
    float val[4];
    val[0] = acc[0] * inv + bflo(yr.x) + bv.x;
    val[1] = acc[1] * inv + bfhi(yr.x) + bv.y;
    val[2] = acc[2] * inv + bflo(yr.y) + bv.z;
    val[3] = acc[3] * inv + bfhi(yr.y) + bv.w;
    float mx = fmaxf(fmaxf(val[0], val[1]), fmaxf(val[2], val[3]));
#pragma unroll
    for (int off = 32; off > 0; off >>= 1) mx = fmaxf(mx, __shfl_xor(mx, off));
    float s = expf(val[0] - mx) + expf(val[1] - mx) + expf(val[2] - mx) + expf(val[3] - mx);
#pragma unroll
    for (int off = 32; off > 0; off >>= 1) s += __shfl_xor(s, off);
    float lse = mx + logf(s);
    float4 o = make_float4(val[0] - lse, val[1] - lse, val[2] - lse, val[3] - lse);
    ((float4*)O)[(size_t)node * 64 + lane] = o;
}

// ---------------------------------------------------------------------------
extern "C" void kernel_launch(void* const* d_in, const int* in_sizes, int n_in,
                              void* d_out, int out_size, void* d_ws, size_t ws_size,
                              hipStream_t stream) {
    const float* x   = (const float*)d_in[0];
    const int*   ei1 = (const int*)d_in[1];
    const int*   ei2 = (const int*)d_in[2];
    const float* W1l = (const float*)d_in[3];
    const float* b1  = (const float*)d_in[4];
    const float* W1r = (const float*)d_in[5];
    const float* W2l = (const float*)d_in[6];
    const float* b2  = (const float*)d_in[7];
    const float* W2r = (const float*)d_in[8];
    float* out = (float*)d_out;

    const int N  = in_sizes[0] / DIN;
    const int E1 = in_sizes[1] / 2;
    const int E2 = in_sizes[2] / 2;
    const int Emax = (E1 > E2) ? E1 : E2;
    const int NB = (N + SCAN_B - 1) / SCAN_B;

    // Workspace layout
    unsigned short* x_bf  = (unsigned short*)d_ws;             // N*512 bf16
    unsigned short* h_bf  = x_bf + (size_t)N * 512;            // N*512 bf16
    unsigned char*  c1l   = (unsigned char*)(h_bf + (size_t)N * 512);  // N*512 fp8
    unsigned short* c1r   = (unsigned short*)(c1l + (size_t)N * 512);  // N*512 bf16
    // layer-2 C buffers alias the (dead-by-then) c1 region
    unsigned char*  c2l   = c1l;                               // N*256 fp8
    unsigned short* c2r   = (unsigned short*)(c2l + (size_t)N * 256);  // N*256 bf16
    unsigned short* w1_bf = c1r + (size_t)N * 512;             // 1024*512
    unsigned short* w2_bf = w1_bf + 1024 * 512;                // 512*512
    int* rowptr1 = (int*)(w2_bf + 512 * 512);                  // N+1
    int* rowptr2 = rowptr1 + (N + 1);                          // N+1
    int* cursor1 = rowptr2 + (N + 1);                          // N
    int* cursor2 = cursor1 + N;                                // N
    int* deg1    = cursor2 + N;                                // N
    int* deg2    = deg1 + N;                                   // N
    int* part1   = deg2 + N;                                   // 256
    int* part2   = part1 + 256;                                // 256
    int* col1    = part2 + 256;                                // E1
    int* col2    = col1 + E1;                                  // E2
    (void)ws_size; (void)n_in; (void)out_size;

    // conversions
    {
        int n8 = N * 512 / 8;
        k_f2bf<<<(n8 + 255) / 256, 256, 0, stream>>>(x, x_bf, n8);
        k_wcvt<<<(98304 + 255) / 256, 256, 0, stream>>>(W1l, W1r, W2l, W2r, w1_bf, w2_bf);
    }

    // both CSRs, batched
    hipMemsetAsync(deg1, 0, (size_t)2 * N * sizeof(int), stream);
    {
        dim3 ge((Emax + 255) / 256, 2);
        k_count2<<<ge, 256, 0, stream>>>(ei1 + E1, ei2 + E2, deg1, deg2, E1, E2);
        k_scan_partial2<<<dim3(NB, 2), SCAN_B, 0, stream>>>(deg1, deg2, part1, part2, N);
        k_scan_part2b<<<2, SCAN_B, 0, stream>>>(part1, part2, NB, rowptr1, rowptr2, N);
        k_scan_final2<<<dim3(NB, 2), SCAN_B, 0, stream>>>(deg1, deg2, part1, part2,
                                                          rowptr1, rowptr2, cursor1, cursor2, N);
        k_fill2<<<ge, 256, 0, stream>>>(ei1, ei1 + E1, ei2, ei2 + E2,
                                        cursor1, cursor2, col1, col2, E1, E2);
    }

    const int MB = (N + TM - 1) / TM;            // 391 row tiles
    const int G8 = (MB + 7) / 8;                 // 49 groups of 8

    // Layer 1: [y_l|y_r] = x @ [W1l;W1r]^T; y_l -> fp8, y_r -> bf16.
    k_gemm_mfma<8, 1><<<G8 * 8 * 8, 256, 0, stream>>>(x_bf, w1_bf, c1l, c1r, N, DIN, 1024);
    k_agg_relu<<<(N + 3) / 4, 256, 0, stream>>>(c1l, c1r, rowptr1, col1, b1, h_bf, N);

    // Layer 2: [y_l|y_r] = h @ [W2l;W2r]^T; y_l -> fp8, y_r -> bf16.
    k_gemm_mfma<4, 1><<<G8 * 8 * 4, 256, 0, stream>>>(h_bf, w2_bf, c2l, c2r, N, DHID, 512);
    k_agg_lsm<<<(N + 3) / 4, 256, 0, stream>>>(c2l, c2r, rowptr2, col2, b2, out, N);
}